// Round 2
// baseline (519.629 us; speedup 1.0000x reference)
//
#include <hip/hip_runtime.h>

// ---------------------------------------------------------------------------
// LinformerAttention on MI355X (gfx950) — round 9.
// B=4, N=4096, C=1024, H=16, K_LM=256, d=64.
// vs round 8 (452 us, qkv 114.6 us @ MfmaUtil 39%):
//  (a) pipe256: B half-tiles held in registers (bF0,bF1), quadrant order
//      (0,0)(0,1)(1,0)(1,1) -> LDS reads 32 -> 24 b128/wave/K-tile (floor);
//      phase 3 is pure-MFMA, 7 barriers/tile instead of 8.
//      New vmcnt ledger (stage order A0,B0,B1,A1):
//        entering tile t: outstanding [t.B1(2), t.A1(2)]
//        ph0: rd A0,B0 | issue t+1.A0 ->6 | WVM(4) drains t.B1 (ph1 need)
//        ph1: rd B1    | issue t+1.B0 ->6 | WVM(4) drains t.A1 (ph2 need)
//        ph2: rd A1    | issue t+1.B1 ->6 | no wait (ph3 reads nothing)
//        ph3: (regs)   | issue t+1.A1 ->8 | WVM(4) drains t+1.A0,B0 (ph0 need)
//        tail tile: WVM(2) after ph0, WVM(0) after ph1.
//  (b) lm_gemm+lm_reduce fused -> lm_fused: no f32 pK/pV round-trip
//      (-128 MB HBM), full-N accumulation, double-buffered staging with
//      counted vmcnt(6) (1 block/CU has no TLP to hide latency), both-sides
//      XOR swizzle (slot ^= (row>>1)&3) kills the 8-way ds_read conflict.
// ---------------------------------------------------------------------------

typedef unsigned short ushort_t;
typedef float f32x4 __attribute__((ext_vector_type(4)));
typedef __bf16 bf16x8 __attribute__((ext_vector_type(8)));
typedef unsigned short ushort8 __attribute__((ext_vector_type(8)));
typedef unsigned short ushort4_t __attribute__((ext_vector_type(4)));

__device__ inline ushort_t f2bf(float f) {
  unsigned int u = __float_as_uint(f);
  u += 0x7fff + ((u >> 16) & 1);   // RNE
  return (ushort_t)(u >> 16);
}

// async global -> LDS, 16 B per lane. LDS dest is wave-uniform base + lane*16.
__device__ inline void gload_lds16(const ushort_t* g, ushort_t* l) {
  __builtin_amdgcn_global_load_lds(
      (const __attribute__((address_space(1))) void*)g,
      (__attribute__((address_space(3))) void*)l, 16, 0, 0);
}

// --------------- fused f32 -> bf16 convert of all four inputs --------------
__global__ __launch_bounds__(256) void cvt_all(
    const float* __restrict__ x,  ushort_t* __restrict__ xo,
    const float* __restrict__ w1, ushort_t* __restrict__ w1o,
    const float* __restrict__ e,  ushort_t* __restrict__ eo,
    const float* __restrict__ w2, ushort_t* __restrict__ w2o) {
  // float4 chunk counts: x 4194304 | Wqkv 786432 | E 4194304 | Wproj 262144
  int i = blockIdx.x * blockDim.x + threadIdx.x;
  const float* in; ushort_t* out; int idx;
  if (i < 4194304)               { in = x;  out = xo;  idx = i; }
  else if (i < 4980736)          { in = w1; out = w1o; idx = i - 4194304; }
  else if (i < 9175040)          { in = e;  out = eo;  idx = i - 4980736; }
  else                           { in = w2; out = w2o; idx = i - 9175040; }
  float4 v = ((const float4*)in)[idx];
  ushort4_t o;
  o.x = f2bf(v.x); o.y = f2bf(v.y); o.z = f2bf(v.z); o.w = f2bf(v.w);
  ((ushort4_t*)out)[idx] = o;
}

// ===========================================================================
// 256x256 8-phase pipelined GEMM core (C = A @ B^T), K = 1024, bf16 in.
// 512 threads = 8 waves as wm(2) x wn(4). Per-wave output 128x64 spread as
// 2x(64 rows) x 2x(32 cols) quadrants; quadrant (mh,nh) touches only LDS
// half-tiles A-h(mh) / B-h(nh).  B fragments for both halves are HELD in
// registers (bF0,bF1) so each LDS byte is read exactly once per K-tile.
// LDS: A slot0 [0,32K) A slot1 [32K,64K) B slot0 [64K,96K) B slot1 [96K,128K).
// Swizzle: 16B slot s within a 128B row holds global k-chunk s ^ (row&7);
// global source pre-permuted, ds_read applies the same XOR.
// ===========================================================================

#define BARX __builtin_amdgcn_s_barrier()
#define WVM(n) do { asm volatile("s_waitcnt vmcnt(" #n ")" ::: "memory"); \
                    __builtin_amdgcn_sched_barrier(0); } while (0)
#define WLG  do { asm volatile("s_waitcnt lgkmcnt(0)" ::: "memory"); \
                  __builtin_amdgcn_sched_barrier(0); } while (0)

#define STG_A(h, slot, tt) do { \
    gload_lds16(sA[h][0] + (tt) * 64, (ushort_t*)(smem + (slot) * 32768 + (h) * 16384 + (w * 2 + 0) * 1024)); \
    gload_lds16(sA[h][1] + (tt) * 64, (ushort_t*)(smem + (slot) * 32768 + (h) * 16384 + (w * 2 + 1) * 1024)); \
  } while (0)
#define STG_B(h, slot, tt) do { \
    gload_lds16(sB[h][0] + (tt) * 64, (ushort_t*)(smem + 65536 + (slot) * 32768 + (h) * 16384 + (w * 2 + 0) * 1024)); \
    gload_lds16(sB[h][1] + (tt) * 64, (ushort_t*)(smem + 65536 + (slot) * 32768 + (h) * 16384 + (w * 2 + 1) * 1024)); \
  } while (0)

#define RD_A(mh) do { \
    const char* ba_ = smem + sl * 32768 + ((mh) * 128 + wm * 64 + l15) * 128; \
    _Pragma("unroll") for (int i_ = 0; i_ < 4; i_++) { \
      aF[i_][0] = *(const bf16x8*)(ba_ + i_ * 2048 + cs0); \
      aF[i_][1] = *(const bf16x8*)(ba_ + i_ * 2048 + cs1); } \
  } while (0)
#define RD_B(nh, BF) do { \
    const char* bb_ = smem + 65536 + sl * 32768 + ((nh) * 128 + wn * 32 + l15) * 128; \
    _Pragma("unroll") for (int j_ = 0; j_ < 2; j_++) { \
      BF[j_][0] = *(const bf16x8*)(bb_ + j_ * 2048 + cs0); \
      BF[j_][1] = *(const bf16x8*)(bb_ + j_ * 2048 + cs1); } \
  } while (0)

#define MQ(mh, nh, BF) do { \
    _Pragma("unroll") for (int i_ = 0; i_ < 4; i_++) \
    _Pragma("unroll") for (int j_ = 0; j_ < 2; j_++) { \
      acc[(mh) * 4 + i_][(nh) * 2 + j_] = __builtin_amdgcn_mfma_f32_16x16x32_bf16( \
          aF[i_][0], BF[j_][0], acc[(mh) * 4 + i_][(nh) * 2 + j_], 0, 0, 0); \
      acc[(mh) * 4 + i_][(nh) * 2 + j_] = __builtin_amdgcn_mfma_f32_16x16x32_bf16( \
          aF[i_][1], BF[j_][1], acc[(mh) * 4 + i_][(nh) * 2 + j_], 0, 0, 0); } \
  } while (0)

__device__ __attribute__((always_inline)) inline void pipe256(
    const ushort_t* __restrict__ Ag, const ushort_t* __restrict__ Bg,
    long long m0, long long n0, char* smem, f32x4 acc[8][4]) {
  const int tid = threadIdx.x, lane = tid & 63, w = tid >> 6;
  const int l15 = lane & 15, quad = lane >> 4;
  const int wm = w >> 2, wn = w & 3;
  const int sw = l15 & 7;
  const int K = 1024;
  // swizzled ds_read byte offsets within a 128 B row, for k-step 0 / 1
  const int cs0 = ((0 * 4 + quad) ^ sw) << 4;
  const int cs1 = ((1 * 4 + quad) ^ sw) << 4;
  // staging source: lane L of chunk c=(w*2+q) covers LDS row c*8+(L>>3),
  // slot L&7 -> global k-chunk (L&7)^((L>>3)&7)  (row&7 == (L>>3)&7).
  const int lr8 = lane >> 3;
  const int sdat = ((lane & 7) ^ lr8) * 8;
  const ushort_t* sA[2][2];
  const ushort_t* sB[2][2];
#pragma unroll
  for (int h = 0; h < 2; h++)
#pragma unroll
    for (int q = 0; q < 2; q++) {
      sA[h][q] = Ag + (m0 + h * 128 + (w * 2 + q) * 8 + lr8) * K + sdat;
      sB[h][q] = Bg + (n0 + h * 128 + (w * 2 + q) * 8 + lr8) * K + sdat;
    }

  const f32x4 zz = {0.f, 0.f, 0.f, 0.f};
#pragma unroll
  for (int i = 0; i < 8; i++)
#pragma unroll
    for (int j = 0; j < 4; j++) acc[i][j] = zz;

  bf16x8 aF[4][2];                 // current A half (refreshed per mh)
  bf16x8 bF0[2][2], bF1[2][2];     // BOTH B halves held across the tile

  // prologue: stage tile 0 in steady-state order A0,B0,B1,A1
  STG_A(0, 0, 0); STG_B(0, 0, 0); STG_B(1, 0, 0); STG_A(1, 0, 0);
  WVM(4);   // A0,B0 ready; [B1,A1] in flight
  BARX;

#pragma unroll 2
  for (int t = 0; t < 15; ++t) {
    const int sl = t & 1, sn = sl ^ 1;
    // ---- phase 0: quadrant (0,0)
    RD_A(0); RD_B(0, bF0);
    STG_A(0, sn, t + 1);
    BARX; WLG;
    __builtin_amdgcn_s_setprio(1); MQ(0, 0, bF0); __builtin_amdgcn_s_setprio(0);
    WVM(4);                    // t.B1 landed
    BARX;
    // ---- phase 1: quadrant (0,1)
    RD_B(1, bF1);
    STG_B(0, sn, t + 1);
    BARX; WLG;
    __builtin_amdgcn_s_setprio(1); MQ(0, 1, bF1); __builtin_amdgcn_s_setprio(0);
    WVM(4);                    // t.A1 landed
    BARX;
    // ---- phase 2: quadrant (1,0)
    RD_A(1);
    STG_B(1, sn, t + 1);
    BARX; WLG;
    __builtin_amdgcn_s_setprio(1); MQ(1, 0, bF0); __builtin_amdgcn_s_setprio(0);
    BARX;
    // ---- phase 3: quadrant (1,1) — pure register MFMA
    STG_A(1, sn, t + 1);
    __builtin_amdgcn_s_setprio(1); MQ(1, 1, bF1); __builtin_amdgcn_s_setprio(0);
    WVM(4);                    // t+1.A0, t+1.B0 landed
    BARX;
  }
  // ---- tail tile t=15 (sl=1), nothing to stage
  {
    const int sl = 1;
    RD_A(0); RD_B(0, bF0);
    BARX; WLG;
    __builtin_amdgcn_s_setprio(1); MQ(0, 0, bF0); __builtin_amdgcn_s_setprio(0);
    WVM(2);
    BARX;
    RD_B(1, bF1);
    BARX; WLG;
    __builtin_amdgcn_s_setprio(1); MQ(0, 1, bF1); __builtin_amdgcn_s_setprio(0);
    WVM(0);
    BARX;
    RD_A(1);
    BARX; WLG;
    __builtin_amdgcn_s_setprio(1); MQ(1, 0, bF0); __builtin_amdgcn_s_setprio(0);
    BARX;
    __builtin_amdgcn_s_setprio(1); MQ(1, 1, bF1); __builtin_amdgcn_s_setprio(0);
  }
}

// --------- fused QKV GEMM + repack:  qkv = x @ Wqkv^T, scatter to q/kT/vT --
// A = x_bf [16384][1024], W = wqkv_bf [3072][1024]. 256x256 tile, 8-phase.
// Grid: 768 blocks; xcd = lin&7 owns m-tiles [xcd*8, xcd*8+8) x all 12 n.
__global__ __launch_bounds__(512) void gemm_qkv(
    const ushort_t* __restrict__ A, const ushort_t* __restrict__ W,
    ushort_t* __restrict__ q, ushort_t* __restrict__ kT, ushort_t* __restrict__ vT) {
  __shared__ __align__(16) char smem[131072];
  const int lin = blockIdx.x;
  const int xcd = lin & 7, rr_ = lin >> 3;          // rr_ 0..95
  const int mt = xcd * 8 + (rr_ & 7);               // 0..63 (m-fastest in chunk)
  const int nt = rr_ >> 3;                          // 0..11
  const long long m0 = (long long)mt * 256;
  const long long n0 = (long long)nt * 256;

  f32x4 acc[8][4];
  pipe256(A, W, m0, n0, smem, acc);

  const int tid = threadIdx.x, lane = tid & 63, w = tid >> 6;
  const int l15 = lane & 15, quad = lane >> 4;
  const int wm = w >> 2, wn = w & 3;
  const int b     = (int)(m0 >> 12);
  const int nrow0 = (int)(m0 & 4095);
  const int s     = (int)(n0 >> 10);          // 0:q 1:k 2:v
  const int ncol0 = (int)(n0 & 1023);
  const int h0    = ncol0 >> 6;

  if (s == 0) {
#pragma unroll
    for (int mh = 0; mh < 2; mh++)
#pragma unroll
      for (int i = 0; i < 4; i++)
#pragma unroll
        for (int nh = 0; nh < 2; nh++)
#pragma unroll
          for (int j = 0; j < 2; j++) {
            int cx = ncol0 + nh * 128 + wn * 32 + j * 16;
            int h  = cx >> 6;
            int dd = (cx & 63) + l15;
            long long z = (long long)b * 16 + h;
            int nb = nrow0 + mh * 128 + wm * 64 + i * 16 + quad * 4;
#pragma unroll
            for (int r = 0; r < 4; r++)
              q[z * 262144 + (long long)(nb + r) * 64 + dd] = f2bf(acc[mh * 4 + i][nh * 2 + j][r]);
          }
  } else {
    // transpose through LDS in two 128-row passes: T[col 256][row 128 +pad]
    ushort_t (*T)[136] = (ushort_t(*)[136])smem;   // 256*136*2 = 69,632 B
    ushort_t* KV = (s == 1) ? kT : vT;
#pragma unroll
    for (int p = 0; p < 2; p++) {
      __syncthreads();
#pragma unroll
      for (int i = 0; i < 4; i++)
#pragma unroll
        for (int nh = 0; nh < 2; nh++)
#pragma unroll
          for (int j = 0; j < 2; j++) {
            int c = nh * 128 + wn * 32 + j * 16 + l15;
            int t = wm * 64 + i * 16 + quad * 4;
            ushort4_t o = {f2bf(acc[p * 4 + i][nh * 2 + j][0]), f2bf(acc[p * 4 + i][nh * 2 + j][1]),
                           f2bf(acc[p * 4 + i][nh * 2 + j][2]), f2bf(acc[p * 4 + i][nh * 2 + j][3])};
            *(ushort4_t*)(&T[c][t]) = o;
          }
      __syncthreads();
#pragma unroll
      for (int it = 0; it < 8; it++) {
        int ch = it * 512 + tid;
        int cl = ch >> 4, tc = (ch & 15) * 8;
        ushort8 v = *(const ushort8*)(&T[cl][tc]);
        int h = h0 + (cl >> 6), dd = cl & 63;
        long long z = (long long)b * 16 + h;
        *(ushort8*)(KV + z * 262144 + (long long)dd * 4096 + (nrow0 + p * 128 + tc)) = v;
      }
    }
  }
}

// ---- fused landmark projection: klm[z][k][d], vlmT[z][d][k] ---------------
//   klm = sum_n E[h][k][n] * kT[z][d][n]  (full N=4096, no split-K)
// Grid 256 blocks (kt 0..3 x z 0..63), 256 threads = 4 waves.
// Double-buffered staging + counted vmcnt(6): 1 block/CU has no TLP, so
// HBM latency must hide under the previous step's compute.
// Bank swizzle: 16B slot s within each 64B row holds global slot
// s ^ ((row>>1)&3); pre-swizzled source + swizzled ds_read (both-sides).
#define LM_STAGE(s_, n_) do { \
    ushort_t* b_ = (ushort_t*)(smemc + (s_) * 24576); \
    _Pragma("unroll") for (int p_ = 0; p_ < 2; p_++) { \
      gload_lds16(gE + (n_) + 32 * p_, b_ + 512 * w + p_ * 2048); \
      gload_lds16(gK + (n_) + 32 * p_, b_ + 4096 + 512 * w + p_ * 2048); \
      gload_lds16(gV + (n_) + 32 * p_, b_ + 8192 + 512 * w + p_ * 2048); \
    } } while (0)

#define LM_COMP(sl_) do { \
    const ushort_t* base_ = (const ushort_t*)(smemc + (sl_) * 24576); \
    _Pragma("unroll") for (int p_ = 0; p_ < 2; p_++) { \
      bf16x8 ef = *(const bf16x8*)(base_ + p_ * 2048 + (w * 16 + l15) * 32 + ((quad ^ swz) * 8)); \
      _Pragma("unroll") for (int j_ = 0; j_ < 4; j_++) { \
        bf16x8 kf = *(const bf16x8*)(base_ + 4096 + p_ * 2048 + (j_ * 16 + l15) * 32 + ((quad ^ swz) * 8)); \
        aK[j_] = __builtin_amdgcn_mfma_f32_16x16x32_bf16(ef, kf, aK[j_], 0, 0, 0); \
        bf16x8 vf = *(const bf16x8*)(base_ + 8192 + p_ * 2048 + (j_ * 16 + l15) * 32 + ((quad ^ swz) * 8)); \
        aV[j_] = __builtin_amdgcn_mfma_f32_16x16x32_bf16(ef, vf, aV[j_], 0, 0, 0); \
      } } } while (0)

__global__ __launch_bounds__(256) void lm_fused(
    const ushort_t* __restrict__ E, const ushort_t* __restrict__ kT,
    const ushort_t* __restrict__ vT, ushort_t* __restrict__ klm,
    ushort_t* __restrict__ vlmT) {
  __shared__ __align__(16) char smemc[49152];   // 2 x 24 KB staging; Tv aliases
  const int tid = threadIdx.x, lane = tid & 63, w = tid >> 6;
  const int l15 = lane & 15, quad = lane >> 4;
  const int bid = blockIdx.x;
  const int xcd = bid & 7, loc = bid >> 3;      // same-z blocks share an XCD
  const int z  = xcd * 8 + (loc >> 2);
  const int kt = loc & 3;
  const int h  = z & 15;
  const int lr = lane >> 2;
  // pre-swizzled source column: slot (lane&3) ^ ((lr>>1)&3), 8-ushort units
  const int lc = ((lane & 3) ^ ((lr >> 1) & 3)) * 8;
  const int swz = (l15 >> 1) & 3;               // read-side swizzle (row = l15 mod 16)

  const ushort_t* gE = E  + ((long long)h * 256 + kt * 64 + 16 * w + lr) * 4096 + lc;
  const ushort_t* gK = kT + ((long long)z * 64 + 16 * w + lr) * 4096 + lc;
  const ushort_t* gV = vT + ((long long)z * 64 + 16 * w + lr) * 4096 + lc;

  const f32x4 zz = {0.f, 0.f, 0.f, 0.f};
  f32x4 aK[4], aV[4];
#pragma unroll
  for (int j = 0; j < 4; j++) { aK[j] = zz; aV[j] = zz; }

  LM_STAGE(0, 0);
#pragma unroll 2
  for (int t = 0; t < 63; ++t) {
    const int sl = t & 1;
    LM_STAGE(sl ^ 1, (t + 1) * 64);    // prefetch next step
    WVM(6);                             // current step's 6 loads landed
    BARX;
    LM_COMP(sl);
    BARX;                               // all reads of sl done before overwrite
  }
  WVM(0);
  BARX;
  LM_COMP(1);                           // t=63

  // ---- epilogue: klm direct, vlmT via LDS transpose ----
  ushort_t* oK = klm + ((long long)z * 256 + kt * 64) * 64;
#pragma unroll
  for (int j = 0; j < 4; j++)
#pragma unroll
    for (int r = 0; r < 4; r++) {
      int row = w * 16 + quad * 4 + r, col = j * 16 + l15;
      oK[row * 64 + col] = f2bf(aK[j][r]);
    }

  __syncthreads();
  float (*Tv)[68] = (float(*)[68])smemc;         // 64*68*4 = 17,408 B
#pragma unroll
  for (int j = 0; j < 4; j++)
#pragma unroll
    for (int r = 0; r < 4; r++)
      Tv[w * 16 + quad * 4 + r][j * 16 + l15] = aV[j][r];
  __syncthreads();
  {
    const int row = tid >> 2, c0 = (tid & 3) * 16;
    ushort8 o0, o1;
#pragma unroll
    for (int i = 0; i < 8; i++) {
      o0[i] = f2bf(Tv[c0 + i][row]);
      o1[i] = f2bf(Tv[c0 + 8 + i][row]);
    }
    ushort_t* dst = vlmT + ((long long)z * 64 + row) * 256 + kt * 64 + c0;
    *(ushort8*)(dst) = o0;
    *(ushort8*)(dst + 8) = o1;
  }
}

// -------- fused flash-style: O = softmax(q@k_lm^T/8) @ v_lm  ---------------
__global__ __launch_bounds__(256) void attn_fused(
    const ushort_t* __restrict__ Q, const ushort_t* __restrict__ Klm,
    const ushort_t* __restrict__ VlmT, ushort_t* __restrict__ O) {
  __shared__ __align__(16) ushort_t smem[16896];          // 33,792 B
  ushort_t (*As)[40]  = (ushort_t(*)[40])smem;            // [64][40]
  ushort_t (*Bs)[40]  = (ushort_t(*)[40])(smem + 2560);   // [256][40]
  ushort_t (*P)[264]  = (ushort_t(*)[264])smem;           // [64][264] (aliases)
  const int tid = threadIdx.x, lane = tid & 63, w = tid >> 6;
  const int l15 = lane & 15, quad = lane >> 4;
  const int z = blockIdx.z;
  const long long m0 = (long long)blockIdx.x * 64;
  const ushort_t* Qb = Q + (long long)z * 262144;
  const ushort_t* Kb = Klm + (long long)z * 16384;
  const ushort_t* Vb = VlmT + (long long)z * 16384;

  const f32x4 zz = {0.f, 0.f, 0.f, 0.f};
  f32x4 acc[16];
#pragma unroll
  for (int j = 0; j < 16; j++) acc[j] = zz;

  const int sr = tid >> 2, sc = (tid & 3) * 8;

  // ---- phase 1: scores S[64][256] in registers ----
  for (int kt = 0; kt < 2; kt++) {
    const int k0 = kt * 32;
    ushort8 av = *(const ushort8*)(Qb + (m0 + sr) * 64 + k0 + sc);
    ushort8 bv[4];
#pragma unroll
    for (int r = 0; r < 4; r++) {
      int c = r * 256 + tid;
      bv[r] = *(const ushort8*)(Kb + (c >> 2) * 64 + k0 + (c & 3) * 8);
    }
    __syncthreads();
    *(ushort8*)(&As[sr][sc]) = av;
#pragma unroll
    for (int r = 0; r < 4; r++) {
      int c = r * 256 + tid;
      *(ushort8*)(&Bs[c >> 2][(c & 3) * 8]) = bv[r];
    }
    __syncthreads();
    bf16x8 af = *(const bf16x8*)(&As[w * 16 + l15][quad * 8]);
#pragma unroll
    for (int j = 0; j < 16; j++) {
      bf16x8 bfj = *(const bf16x8*)(&Bs[j * 16 + l15][quad * 8]);
      acc[j] = __builtin_amdgcn_mfma_f32_16x16x32_bf16(af, bfj, acc[j], 0, 0, 0);
    }
  }

  // ---- phase 2: softmax over 256 landmarks, P -> LDS (D-layout -> A-layout)
  __syncthreads();
#pragma unroll
  for (int r = 0; r < 4; r++) {
    float x[16];
    float vmax = -1e30f;
#pragma unroll
    for (int j = 0; j < 16; j++) { x[j] = acc[j][r] * 0.125f; vmax = fmaxf(vmax, x[j]); }
#pragma unroll
    for (int m = 1; m < 16; m <<= 1) vmax = fmaxf(vmax, __shfl_xor(vmax, m, 64));
    float s = 0.f;
#pragma unroll
    for (int j = 0; j < 16; j++) { x[j] = __expf(x[j] - vmax); s += x[j]; }
#pragma unroll
    for (int m = 1; m < 16; m <<= 1) s += __shfl_xor(s, m, 64);
    float inv = 1.0f / s;
    int row = w * 16 + quad * 4 + r;
#pragma unroll
    for (int j = 0; j < 16; j++)
      P[row][j * 16 + l15] = f2bf(x[j] * inv);
  }
  __syncthreads();

  // ---- phase 3: O[64][64] = P @ VlmT^T ----
  f32x4 o_acc[4];
#pragma unroll
  for (int j = 0; j < 4; j++) o_acc[j] = zz;
#pragma unroll
  for (int kc = 0; kc < 8; kc++) {
    bf16x8 pf = *(const bf16x8*)(&P[w * 16 + l15][kc * 32 + quad * 8]);
#pragma unroll
    for (int j = 0; j < 4; j++) {
      bf16x8 vf = *(const bf16x8*)(Vb + (j * 16 + l15) * 256 + kc * 32 + quad * 8);
      o_acc[j] = __builtin_amdgcn_mfma_f32_16x16x32_bf16(pf, vf, o_acc[j], 0, 0, 0);
    }
  }

#pragma unroll
  for (int j = 0; j < 4; j++)
#pragma unroll
    for (int r = 0; r < 4; r++) {
      int row = w * 16 + quad * 4 + r;
      int col = j * 16 + l15;
      O[(long long)z * 262144 + (m0 + row) * 64 + col] = f2bf(o_acc[j][r]);
    }
}

// ------------------- 256x256 tile NT GEMM, f32 out (+bias) -----------------
// A [16384][1024] bf16, B [1024][1024] bf16, C [16384][1024] f32.
// Grid: 256 blocks; xcd = lin&7 owns m-tiles [xcd*8, xcd*8+8) x all 4 n.
__global__ __launch_bounds__(512) void gemm_nt_256(
    const ushort_t* __restrict__ A, const ushort_t* __restrict__ B,
    float* __restrict__ C, const float* __restrict__ bias) {
  __shared__ __align__(16) char smem[131072];
  const int lin = blockIdx.x;
  const int xcd = lin & 7, rr_ = lin >> 3;          // rr_ 0..31
  const int mt = xcd * 8 + (rr_ & 7);               // 0..63
  const int nt = rr_ >> 3;                          // 0..3
  const long long m0 = (long long)mt * 256;
  const long long n0 = (long long)nt * 256;

  f32x4 acc[8][4];
  pipe256(A, B, m0, n0, smem, acc);

  const int tid = threadIdx.x, lane = tid & 63, w = tid >> 6;
  const int l15 = lane & 15, quad = lane >> 4;
  const int wm = w >> 2, wn = w & 3;

#pragma unroll
  for (int mh = 0; mh < 2; mh++)
#pragma unroll
    for (int i = 0; i < 4; i++)
#pragma unroll
      for (int nh = 0; nh < 2; nh++)
#pragma unroll
        for (int j = 0; j < 2; j++) {
          long long row = m0 + mh * 128 + wm * 64 + i * 16 + quad * 4;
          long long col = n0 + nh * 128 + wn * 32 + j * 16 + l15;
          float bv = bias[col];
#pragma unroll
          for (int r = 0; r < 4; r++)
            C[(row + r) * 1024 + col] = acc[mh * 4 + i][nh * 2 + j][r] + bv;
        }
}

// ---------------------------------------------------------------------------
extern "C" void kernel_launch(void* const* d_in, const int* in_sizes, int n_in,
                              void* d_out, int out_size, void* d_ws, size_t ws_size,
                              hipStream_t stream) {
  const float* x     = (const float*)d_in[0];
  const float* Wqkv  = (const float*)d_in[1];
  const float* E     = (const float*)d_in[2];
  const float* Wproj = (const float*)d_in[3];
  const float* bproj = (const float*)d_in[4];
  float* out = (float*)d_out;

  char* ws = (char*)d_ws;
  ushort_t* x_bf     = (ushort_t*)(ws + 0);            // 32 MB; later attn O
  ushort_t* wqkv_bf  = (ushort_t*)(ws + 33554432);     //  6 MB
  ushort_t* e_bf     = (ushort_t*)(ws + 39845888);     // 32 MB
  ushort_t* wproj_bf = (ushort_t*)(ws + 73400320);     //  2 MB
  ushort_t* q_bf     = (ushort_t*)(ws + 75497472);     // 32 MB
  ushort_t* kT       = (ushort_t*)(ws + 109051904);    // 32 MB
  ushort_t* vT       = (ushort_t*)(ws + 142606336);    // 32 MB
  ushort_t* klm      = (ushort_t*)(ws + 176160768);    //  2 MB
  ushort_t* vlmT     = (ushort_t*)(ws + 178257920);    //  2 MB
  // total: 180,355,072 bytes

  // 1) fused f32 -> bf16 converts (one dispatch)
  cvt_all<<<36864, 256, 0, stream>>>(x, x_bf, Wqkv, wqkv_bf, E, e_bf, Wproj, wproj_bf);

  // 2) fused QKV GEMM + repack -> q(n,d), kT(d,n), vT(d,n) bf16  [8-phase 256^2]
  gemm_qkv<<<768, 512, 0, stream>>>(x_bf, wqkv_bf, q_bf, kT, vT);

  // 3) fused landmark projection (full-N accumulation, no split-K round-trip)
  lm_fused<<<256, 256, 0, stream>>>(e_bf, kT, vT, klm, vlmT);

  // 4) fused scores+softmax+PV -> attn_out (B,H,N,d) contiguous
  attn_fused<<<dim3(64, 1, 64), 256, 0, stream>>>(q_bf, klm, vlmT, x_bf);

  // 5) out = attn_out @ Wproj^T + bproj  [16384 x 1024] f32  [8-phase 256^2]
  gemm_nt_256<<<256, 512, 0, stream>>>(x_bf, wproj_bf, out, bproj);
}

// Round 4
// 450.584 us; speedup vs baseline: 1.1532x; 1.1532x over previous
//
#include <hip/hip_runtime.h>

// ---------------------------------------------------------------------------
// LinformerAttention on MI355X (gfx950) — round 11 (= round 10 resubmitted;
// round-10 bench was lost to GPUAcquisitionTimeout, no data).
// B=4, N=4096, C=1024, H=16, K_LM=256, d=64.
// Round 9 post-mortem: BOTH changes regressed (519 us).
//  - pipe256 B-in-registers: lock-step phases don't benefit from a pure-MFMA
//    phase; register holding across barriers defeated the allocator.
//    -> reverted to round-8 schedule (114.6 us, MfmaUtil 39%).
//  - lm_fused: 256 blocks = 1 block/CU, no TLP, prefetch-1 < HBM latency.
//    -> reverted to split-K lm_gemm (1024 blocks) + lm_reduce.
// Single live experiment: both-sides XOR bank swizzle in lm_gemm
// (slot ^= (row>>1)&3 at 16B granularity; pre-swizzled global source +
// swizzled ds_read) to kill its ~8-way LDS conflict. Everything else is
// byte-identical to round 8 (452 us verified).
// ---------------------------------------------------------------------------

typedef unsigned short ushort_t;
typedef float f32x4 __attribute__((ext_vector_type(4)));
typedef __bf16 bf16x8 __attribute__((ext_vector_type(8)));
typedef unsigned short ushort8 __attribute__((ext_vector_type(8)));
typedef unsigned short ushort4_t __attribute__((ext_vector_type(4)));

__device__ inline ushort_t f2bf(float f) {
  unsigned int u = __float_as_uint(f);
  u += 0x7fff + ((u >> 16) & 1);   // RNE
  return (ushort_t)(u >> 16);
}

// async global -> LDS, 16 B per lane. LDS dest is wave-uniform base + lane*16.
__device__ inline void gload_lds16(const ushort_t* g, ushort_t* l) {
  __builtin_amdgcn_global_load_lds(
      (const __attribute__((address_space(1))) void*)g,
      (__attribute__((address_space(3))) void*)l, 16, 0, 0);
}

// --------------- fused f32 -> bf16 convert of all four inputs --------------
__global__ __launch_bounds__(256) void cvt_all(
    const float* __restrict__ x,  ushort_t* __restrict__ xo,
    const float* __restrict__ w1, ushort_t* __restrict__ w1o,
    const float* __restrict__ e,  ushort_t* __restrict__ eo,
    const float* __restrict__ w2, ushort_t* __restrict__ w2o) {
  // float4 chunk counts: x 4194304 | Wqkv 786432 | E 4194304 | Wproj 262144
  int i = blockIdx.x * blockDim.x + threadIdx.x;
  const float* in; ushort_t* out; int idx;
  if (i < 4194304)               { in = x;  out = xo;  idx = i; }
  else if (i < 4980736)          { in = w1; out = w1o; idx = i - 4194304; }
  else if (i < 9175040)          { in = e;  out = eo;  idx = i - 4980736; }
  else                           { in = w2; out = w2o; idx = i - 9175040; }
  float4 v = ((const float4*)in)[idx];
  ushort4_t o;
  o.x = f2bf(v.x); o.y = f2bf(v.y); o.z = f2bf(v.z); o.w = f2bf(v.w);
  ((ushort4_t*)out)[idx] = o;
}

// ===========================================================================
// 256x256 8-phase pipelined GEMM core (C = A @ B^T), K = 1024, bf16 in.
// 512 threads = 8 waves as wm(2) x wn(4). Per-wave output: two 64-row strips
// x two 32-col strips; quadrant (mh,nh) touches only LDS half-tiles
// A-h(mh) / B-h(nh).  (Round-8 schedule — verified 114.6 us.)
// LDS: A slot0 [0,32K) A slot1 [32K,64K) B slot0 [64K,96K) B slot1 [96K,128K).
// Swizzle: 16B slot s within a 128B row holds global k-chunk s ^ (row&7);
// global source pre-permuted, ds_read applies the same XOR.
// vmcnt ledger (stage order per tile [A0,B0,A1,B1], quadrants (0,0)(1,0)
// (1,1)(0,1)): waits 4/4/-/4, tail 2/0/-/-.
// ===========================================================================

#define BARX __builtin_amdgcn_s_barrier()
#define WVM(n) do { asm volatile("s_waitcnt vmcnt(" #n ")" ::: "memory"); \
                    __builtin_amdgcn_sched_barrier(0); } while (0)
#define WLG  do { asm volatile("s_waitcnt lgkmcnt(0)" ::: "memory"); \
                  __builtin_amdgcn_sched_barrier(0); } while (0)

#define STG_A(h, slot, tt) do { \
    gload_lds16(sA[h][0] + (tt) * 64, (ushort_t*)(smem + (slot) * 32768 + (h) * 16384 + (w * 2 + 0) * 1024)); \
    gload_lds16(sA[h][1] + (tt) * 64, (ushort_t*)(smem + (slot) * 32768 + (h) * 16384 + (w * 2 + 1) * 1024)); \
  } while (0)
#define STG_B(h, slot, tt) do { \
    gload_lds16(sB[h][0] + (tt) * 64, (ushort_t*)(smem + 65536 + (slot) * 32768 + (h) * 16384 + (w * 2 + 0) * 1024)); \
    gload_lds16(sB[h][1] + (tt) * 64, (ushort_t*)(smem + 65536 + (slot) * 32768 + (h) * 16384 + (w * 2 + 1) * 1024)); \
  } while (0)

#define RD_A(mh) do { \
    const char* ba_ = smem + sl * 32768 + ((mh) * 128 + wm * 64 + l15) * 128; \
    _Pragma("unroll") for (int i_ = 0; i_ < 4; i_++) { \
      aF[i_][0] = *(const bf16x8*)(ba_ + i_ * 2048 + cs0); \
      aF[i_][1] = *(const bf16x8*)(ba_ + i_ * 2048 + cs1); } \
  } while (0)
#define RD_B(nh) do { \
    const char* bb_ = smem + 65536 + sl * 32768 + ((nh) * 128 + wn * 32 + l15) * 128; \
    _Pragma("unroll") for (int j_ = 0; j_ < 2; j_++) { \
      bF[j_][0] = *(const bf16x8*)(bb_ + j_ * 2048 + cs0); \
      bF[j_][1] = *(const bf16x8*)(bb_ + j_ * 2048 + cs1); } \
  } while (0)

#define MQ(mh, nh) do { \
    _Pragma("unroll") for (int i_ = 0; i_ < 4; i_++) \
    _Pragma("unroll") for (int j_ = 0; j_ < 2; j_++) { \
      acc[(mh) * 4 + i_][(nh) * 2 + j_] = __builtin_amdgcn_mfma_f32_16x16x32_bf16( \
          aF[i_][0], bF[j_][0], acc[(mh) * 4 + i_][(nh) * 2 + j_], 0, 0, 0); \
      acc[(mh) * 4 + i_][(nh) * 2 + j_] = __builtin_amdgcn_mfma_f32_16x16x32_bf16( \
          aF[i_][1], bF[j_][1], acc[(mh) * 4 + i_][(nh) * 2 + j_], 0, 0, 0); } \
  } while (0)

__device__ __attribute__((always_inline)) inline void pipe256(
    const ushort_t* __restrict__ Ag, const ushort_t* __restrict__ Bg,
    long long m0, long long n0, char* smem, f32x4 acc[8][4]) {
  const int tid = threadIdx.x, lane = tid & 63, w = tid >> 6;
  const int l15 = lane & 15, quad = lane >> 4;
  const int wm = w >> 2, wn = w & 3;
  const int sw = l15 & 7;
  const int K = 1024;
  // swizzled ds_read byte offsets within a 128 B row, for k-step 0 / 1
  const int cs0 = ((0 * 4 + quad) ^ sw) << 4;
  const int cs1 = ((1 * 4 + quad) ^ sw) << 4;
  // staging source: lane L of chunk c=(w*2+q) covers LDS row c*8+(L>>3),
  // slot L&7 -> global k-chunk (L&7)^((L>>3)&7)  (row&7 == (L>>3)&7).
  const int lr8 = lane >> 3;
  const int sdat = ((lane & 7) ^ lr8) * 8;
  const ushort_t* sA[2][2];
  const ushort_t* sB[2][2];
#pragma unroll
  for (int h = 0; h < 2; h++)
#pragma unroll
    for (int q = 0; q < 2; q++) {
      sA[h][q] = Ag + (m0 + h * 128 + (w * 2 + q) * 8 + lr8) * K + sdat;
      sB[h][q] = Bg + (n0 + h * 128 + (w * 2 + q) * 8 + lr8) * K + sdat;
    }

  const f32x4 zz = {0.f, 0.f, 0.f, 0.f};
#pragma unroll
  for (int i = 0; i < 8; i++)
#pragma unroll
    for (int j = 0; j < 4; j++) acc[i][j] = zz;

  bf16x8 aF[4][2];   // current A half (re-read per quadrant as needed)
  bf16x8 bF[2][2];   // current B half

  // prologue: stage tile 0 (order A0,B0,A1,B1); need A0,B0 before ph0
  STG_A(0, 0, 0); STG_B(0, 0, 0); STG_A(1, 0, 0); STG_B(1, 0, 0);
  WVM(4);
  BARX;

#pragma unroll 2
  for (int t = 0; t < 16; ++t) {
    const int sl = t & 1, sn = sl ^ 1;
    const bool pf = (t < 15);
    // ---- phase 0: quadrant (0,0)
    RD_A(0); RD_B(0);
    if (pf) STG_A(0, sn, t + 1);
    BARX; WLG;
    __builtin_amdgcn_s_setprio(1); MQ(0, 0); __builtin_amdgcn_s_setprio(0);
    if (pf) { WVM(4); } else { WVM(2); }
    BARX;
    // ---- phase 1: quadrant (1,0)
    RD_A(1);
    if (pf) STG_B(0, sn, t + 1);
    BARX; WLG;
    __builtin_amdgcn_s_setprio(1); MQ(1, 0); __builtin_amdgcn_s_setprio(0);
    if (pf) { WVM(4); } else { WVM(0); }
    BARX;
    // ---- phase 2: quadrant (1,1)
    RD_B(1);
    if (pf) STG_A(1, sn, t + 1);
    BARX; WLG;
    __builtin_amdgcn_s_setprio(1); MQ(1, 1); __builtin_amdgcn_s_setprio(0);
    BARX;
    // ---- phase 3: quadrant (0,1)
    RD_A(0);
    if (pf) STG_B(1, sn, t + 1);
    BARX; WLG;
    __builtin_amdgcn_s_setprio(1); MQ(0, 1); __builtin_amdgcn_s_setprio(0);
    if (pf) WVM(4);
    BARX;
  }
}

// --------- fused QKV GEMM + repack:  qkv = x @ Wqkv^T, scatter to q/kT/vT --
// A = x_bf [16384][1024], W = wqkv_bf [3072][1024]. 256x256 tile, 8-phase.
// Grid: 768 blocks; xcd = lin&7 owns m-tiles [xcd*8, xcd*8+8) x all 12 n.
__global__ __launch_bounds__(512) void gemm_qkv(
    const ushort_t* __restrict__ A, const ushort_t* __restrict__ W,
    ushort_t* __restrict__ q, ushort_t* __restrict__ kT, ushort_t* __restrict__ vT) {
  __shared__ __align__(16) char smem[131072];
  const int lin = blockIdx.x;
  const int xcd = lin & 7, rr_ = lin >> 3;          // rr_ 0..95
  const int mt = xcd * 8 + (rr_ & 7);               // 0..63 (m-fastest in chunk)
  const int nt = rr_ >> 3;                          // 0..11
  const long long m0 = (long long)mt * 256;
  const long long n0 = (long long)nt * 256;

  f32x4 acc[8][4];
  pipe256(A, W, m0, n0, smem, acc);

  const int tid = threadIdx.x, lane = tid & 63, w = tid >> 6;
  const int l15 = lane & 15, quad = lane >> 4;
  const int wm = w >> 2, wn = w & 3;
  const int b     = (int)(m0 >> 12);
  const int nrow0 = (int)(m0 & 4095);
  const int s     = (int)(n0 >> 10);          // 0:q 1:k 2:v
  const int ncol0 = (int)(n0 & 1023);
  const int h0    = ncol0 >> 6;

  if (s == 0) {
#pragma unroll
    for (int mh = 0; mh < 2; mh++)
#pragma unroll
      for (int i = 0; i < 4; i++)
#pragma unroll
        for (int nh = 0; nh < 2; nh++)
#pragma unroll
          for (int j = 0; j < 2; j++) {
            int cx = ncol0 + nh * 128 + wn * 32 + j * 16;
            int h  = cx >> 6;
            int dd = (cx & 63) + l15;
            long long z = (long long)b * 16 + h;
            int nb = nrow0 + mh * 128 + wm * 64 + i * 16 + quad * 4;
#pragma unroll
            for (int r = 0; r < 4; r++)
              q[z * 262144 + (long long)(nb + r) * 64 + dd] = f2bf(acc[mh * 4 + i][nh * 2 + j][r]);
          }
  } else {
    // transpose through LDS in two 128-row passes: T[col 256][row 128 +pad]
    ushort_t (*T)[136] = (ushort_t(*)[136])smem;   // 256*136*2 = 69,632 B
    ushort_t* KV = (s == 1) ? kT : vT;
#pragma unroll
    for (int p = 0; p < 2; p++) {
      __syncthreads();
#pragma unroll
      for (int i = 0; i < 4; i++)
#pragma unroll
        for (int nh = 0; nh < 2; nh++)
#pragma unroll
          for (int j = 0; j < 2; j++) {
            int c = nh * 128 + wn * 32 + j * 16 + l15;
            int t = wm * 64 + i * 16 + quad * 4;
            ushort4_t o = {f2bf(acc[p * 4 + i][nh * 2 + j][0]), f2bf(acc[p * 4 + i][nh * 2 + j][1]),
                           f2bf(acc[p * 4 + i][nh * 2 + j][2]), f2bf(acc[p * 4 + i][nh * 2 + j][3])};
            *(ushort4_t*)(&T[c][t]) = o;
          }
      __syncthreads();
#pragma unroll
      for (int it = 0; it < 8; it++) {
        int ch = it * 512 + tid;
        int cl = ch >> 4, tc = (ch & 15) * 8;
        ushort8 v = *(const ushort8*)(&T[cl][tc]);
        int h = h0 + (cl >> 6), dd = cl & 63;
        long long z = (long long)b * 16 + h;
        *(ushort8*)(KV + z * 262144 + (long long)dd * 4096 + (nrow0 + p * 128 + tc)) = v;
      }
    }
  }
}

// ---- fused landmark partials: pK/pV[(z*4+s)*16384 + k*64 + d] -------------
//   = sum_{n in split s} E[h][k][n] * {kT,vT}[z][d][n]
// Round-8 structure (1024 blocks, 4/CU for TLP) + NEW both-sides XOR swizzle:
// 16B slot s within each 64B LDS row holds global chunk s ^ ((row>>1)&3);
// global source pre-permuted (rule 21), ds_read applies the same XOR.
__global__ __launch_bounds__(256) void lm_gemm(
    const ushort_t* __restrict__ E, const ushort_t* __restrict__ kT,
    const ushort_t* __restrict__ vT, float* __restrict__ pK, float* __restrict__ pV) {
  __shared__ __align__(16) ushort_t smem[12288];  // E:0,2048  K:4096,6144  V:8192,10240
  const int tid = threadIdx.x, lane = tid & 63, w = tid >> 6;
  const int l15 = lane & 15, quad = lane >> 4;
  const int kt = blockIdx.x;       // k-tile 0..3
  const int s  = blockIdx.y;       // split 0..3
  const int z  = blockIdx.z;       // 0..63
  const int h  = z & 15;
  const int lr = lane >> 2;
  // pre-swizzled source column: chunk (lane&3) ^ ((lr>>1)&3), in 8-ushort units
  const int lc = ((lane & 3) ^ ((lr >> 1) & 3)) * 8;
  const int swz = (l15 >> 1) & 3;  // read-side swizzle (row & 15 == l15)

  const ushort_t* gE = E  + ((long long)h * 256 + kt * 64 + 16 * w + lr) * 4096 + s * 1024 + lc;
  const ushort_t* gK = kT + ((long long)z * 64 + 16 * w + lr) * 4096 + s * 1024 + lc;
  const ushort_t* gV = vT + ((long long)z * 64 + 16 * w + lr) * 4096 + s * 1024 + lc;
  ushort_t* lE = smem + 512 * w;
  ushort_t* lK = smem + 4096 + 512 * w;
  ushort_t* lV = smem + 8192 + 512 * w;

  const f32x4 zz = {0.f, 0.f, 0.f, 0.f};
  f32x4 aK[4], aV[4];
#pragma unroll
  for (int j = 0; j < 4; j++) { aK[j] = zz; aV[j] = zz; }

  for (int n = 0; n < 1024; n += 64) {
    __syncthreads();
#pragma unroll
    for (int p = 0; p < 2; p++) {
      gload_lds16(gE + n + 32 * p, lE + p * 2048);
      gload_lds16(gK + n + 32 * p, lK + p * 2048);
      gload_lds16(gV + n + 32 * p, lV + p * 2048);
    }
    __syncthreads();
#pragma unroll
    for (int p = 0; p < 2; p++) {
      bf16x8 ef = *(const bf16x8*)(smem + p * 2048 + (w * 16 + l15) * 32 + ((quad ^ swz) * 8));
#pragma unroll
      for (int j = 0; j < 4; j++) {
        bf16x8 kf = *(const bf16x8*)(smem + 4096 + p * 2048 + (j * 16 + l15) * 32 + ((quad ^ swz) * 8));
        aK[j] = __builtin_amdgcn_mfma_f32_16x16x32_bf16(ef, kf, aK[j], 0, 0, 0);
        bf16x8 vf = *(const bf16x8*)(smem + 8192 + p * 2048 + (j * 16 + l15) * 32 + ((quad ^ swz) * 8));
        aV[j] = __builtin_amdgcn_mfma_f32_16x16x32_bf16(ef, vf, aV[j], 0, 0, 0);
      }
    }
  }

  float* oK = pK + ((long long)(z * 4 + s) * 256 + kt * 64) * 64;
  float* oV = pV + ((long long)(z * 4 + s) * 256 + kt * 64) * 64;
#pragma unroll
  for (int j = 0; j < 4; j++)
#pragma unroll
    for (int r = 0; r < 4; r++) {
      int row = w * 16 + quad * 4 + r, col = j * 16 + l15;
      oK[row * 64 + col] = aK[j][r];
      oV[row * 64 + col] = aV[j][r];
    }
}

// ---- reduce 4 splits -> klm[z][k][d] bf16 and vlmT[z][d][k] bf16 ----------
__global__ __launch_bounds__(256) void lm_reduce(
    const float* __restrict__ pK, const float* __restrict__ pV,
    ushort_t* __restrict__ klm, ushort_t* __restrict__ vlmT) {
  __shared__ float Tv[64][68];
  const int tid = threadIdx.x;
  const int kt = blockIdx.x;   // 0..3
  const int z  = blockIdx.y;   // 0..63
  const long long base = (long long)z * 4 * 16384 + kt * 64 * 64;
  const int row = tid >> 2, c0 = (tid & 3) * 16;

  float sk[16];
#pragma unroll
  for (int g = 0; g < 4; g++) {
    f32x4 a = {0.f, 0.f, 0.f, 0.f};
#pragma unroll
    for (int s = 0; s < 4; s++)
      a += *(const f32x4*)(pK + base + (long long)s * 16384 + row * 64 + c0 + g * 4);
    sk[g * 4 + 0] = a[0]; sk[g * 4 + 1] = a[1]; sk[g * 4 + 2] = a[2]; sk[g * 4 + 3] = a[3];
  }
  {
    ushort_t* dst = klm + ((long long)z * 256 + kt * 64 + row) * 64 + c0;
    ushort8 o0, o1;
#pragma unroll
    for (int i = 0; i < 8; i++) { o0[i] = f2bf(sk[i]); o1[i] = f2bf(sk[8 + i]); }
    *(ushort8*)(dst) = o0;
    *(ushort8*)(dst + 8) = o1;
  }

#pragma unroll
  for (int g = 0; g < 4; g++) {
    f32x4 a = {0.f, 0.f, 0.f, 0.f};
#pragma unroll
    for (int s = 0; s < 4; s++)
      a += *(const f32x4*)(pV + base + (long long)s * 16384 + row * 64 + c0 + g * 4);
    *(f32x4*)(&Tv[row][c0 + g * 4]) = a;
  }
  __syncthreads();
  {
    ushort8 o0, o1;
#pragma unroll
    for (int i = 0; i < 8; i++) {
      o0[i] = f2bf(Tv[c0 + i][row]);
      o1[i] = f2bf(Tv[c0 + 8 + i][row]);
    }
    ushort_t* dst = vlmT + ((long long)z * 64 + row) * 256 + kt * 64 + c0;
    *(ushort8*)(dst) = o0;
    *(ushort8*)(dst + 8) = o1;
  }
}

// -------- fused flash-style: O = softmax(q@k_lm^T/8) @ v_lm  ---------------
__global__ __launch_bounds__(256) void attn_fused(
    const ushort_t* __restrict__ Q, const ushort_t* __restrict__ Klm,
    const ushort_t* __restrict__ VlmT, ushort_t* __restrict__ O) {
  __shared__ __align__(16) ushort_t smem[16896];          // 33,792 B
  ushort_t (*As)[40]  = (ushort_t(*)[40])smem;            // [64][40]
  ushort_t (*Bs)[40]  = (ushort_t(*)[40])(smem + 2560);   // [256][40]
  ushort_t (*P)[264]  = (ushort_t(*)[264])smem;           // [64][264] (aliases)
  const int tid = threadIdx.x, lane = tid & 63, w = tid >> 6;
  const int l15 = lane & 15, quad = lane >> 4;
  const int z = blockIdx.z;
  const long long m0 = (long long)blockIdx.x * 64;
  const ushort_t* Qb = Q + (long long)z * 262144;
  const ushort_t* Kb = Klm + (long long)z * 16384;
  const ushort_t* Vb = VlmT + (long long)z * 16384;

  const f32x4 zz = {0.f, 0.f, 0.f, 0.f};
  f32x4 acc[16];
#pragma unroll
  for (int j = 0; j < 16; j++) acc[j] = zz;

  const int sr = tid >> 2, sc = (tid & 3) * 8;

  // ---- phase 1: scores S[64][256] in registers ----
  for (int kt = 0; kt < 2; kt++) {
    const int k0 = kt * 32;
    ushort8 av = *(const ushort8*)(Qb + (m0 + sr) * 64 + k0 + sc);
    ushort8 bv[4];
#pragma unroll
    for (int r = 0; r < 4; r++) {
      int c = r * 256 + tid;
      bv[r] = *(const ushort8*)(Kb + (c >> 2) * 64 + k0 + (c & 3) * 8);
    }
    __syncthreads();
    *(ushort8*)(&As[sr][sc]) = av;
#pragma unroll
    for (int r = 0; r < 4; r++) {
      int c = r * 256 + tid;
      *(ushort8*)(&Bs[c >> 2][(c & 3) * 8]) = bv[r];
    }
    __syncthreads();
    bf16x8 af = *(const bf16x8*)(&As[w * 16 + l15][quad * 8]);
#pragma unroll
    for (int j = 0; j < 16; j++) {
      bf16x8 bfj = *(const bf16x8*)(&Bs[j * 16 + l15][quad * 8]);
      acc[j] = __builtin_amdgcn_mfma_f32_16x16x32_bf16(af, bfj, acc[j], 0, 0, 0);
    }
  }

  // ---- phase 2: softmax over 256 landmarks, P -> LDS (D-layout -> A-layout)
  __syncthreads();
#pragma unroll
  for (int r = 0; r < 4; r++) {
    float x[16];
    float vmax = -1e30f;
#pragma unroll
    for (int j = 0; j < 16; j++) { x[j] = acc[j][r] * 0.125f; vmax = fmaxf(vmax, x[j]); }
#pragma unroll
    for (int m = 1; m < 16; m <<= 1) vmax = fmaxf(vmax, __shfl_xor(vmax, m, 64));
    float s = 0.f;
#pragma unroll
    for (int j = 0; j < 16; j++) { x[j] = __expf(x[j] - vmax); s += x[j]; }
#pragma unroll
    for (int m = 1; m < 16; m <<= 1) s += __shfl_xor(s, m, 64);
    float inv = 1.0f / s;
    int row = w * 16 + quad * 4 + r;
#pragma unroll
    for (int j = 0; j < 16; j++)
      P[row][j * 16 + l15] = f2bf(x[j] * inv);
  }
  __syncthreads();

  // ---- phase 3: O[64][64] = P @ VlmT^T ----
  f32x4 o_acc[4];
#pragma unroll
  for (int j = 0; j < 4; j++) o_acc[j] = zz;
#pragma unroll
  for (int kc = 0; kc < 8; kc++) {
    bf16x8 pf = *(const bf16x8*)(&P[w * 16 + l15][kc * 32 + quad * 8]);
#pragma unroll
    for (int j = 0; j < 4; j++) {
      bf16x8 vf = *(const bf16x8*)(Vb + (j * 16 + l15) * 256 + kc * 32 + quad * 8);
      o_acc[j] = __builtin_amdgcn_mfma_f32_16x16x32_bf16(pf, vf, o_acc[j], 0, 0, 0);
    }
  }

#pragma unroll
  for (int j = 0; j < 4; j++)
#pragma unroll
    for (int r = 0; r < 4; r++) {
      int row = w * 16 + quad * 4 + r;
      int col = j * 16 + l15;
      O[(long long)z * 262144 + (m0 + row) * 64 + col] = f2bf(o_acc[j][r]);
    }
}

// ------------------- 256x256 tile NT GEMM, f32 out (+bias) -----------------
// A [16384][1024] bf16, B [1024][1024] bf16, C [16384][1024] f32.
// Grid: 256 blocks; xcd = lin&7 owns m-tiles [xcd*8, xcd*8+8) x all 4 n.
__global__ __launch_bounds__(512) void gemm_nt_256(
    const ushort_t* __restrict__ A, const ushort_t* __restrict__ B,
    float* __restrict__ C, const float* __restrict__ bias) {
  __shared__ __align__(16) char smem[131072];
  const int lin = blockIdx.x;
  const int xcd = lin & 7, rr_ = lin >> 3;          // rr_ 0..31
  const int mt = xcd * 8 + (rr_ & 7);               // 0..63
  const int nt = rr_ >> 3;                          // 0..3
  const long long m0 = (long long)mt * 256;
  const long long n0 = (long long)nt * 256;

  f32x4 acc[8][4];
  pipe256(A, B, m0, n0, smem, acc);

  const int tid = threadIdx.x, lane = tid & 63, w = tid >> 6;
  const int l15 = lane & 15, quad = lane >> 4;
  const int wm = w >> 2, wn = w & 3;

#pragma unroll
  for (int mh = 0; mh < 2; mh++)
#pragma unroll
    for (int i = 0; i < 4; i++)
#pragma unroll
      for (int nh = 0; nh < 2; nh++)
#pragma unroll
        for (int j = 0; j < 2; j++) {
          long long row = m0 + mh * 128 + wm * 64 + i * 16 + quad * 4;
          long long col = n0 + nh * 128 + wn * 32 + j * 16 + l15;
          float bv = bias[col];
#pragma unroll
          for (int r = 0; r < 4; r++)
            C[(row + r) * 1024 + col] = acc[mh * 4 + i][nh * 2 + j][r] + bv;
        }
}

// ---------------------------------------------------------------------------
extern "C" void kernel_launch(void* const* d_in, const int* in_sizes, int n_in,
                              void* d_out, int out_size, void* d_ws, size_t ws_size,
                              hipStream_t stream) {
  const float* x     = (const float*)d_in[0];
  const float* Wqkv  = (const float*)d_in[1];
  const float* E     = (const float*)d_in[2];
  const float* Wproj = (const float*)d_in[3];
  const float* bproj = (const float*)d_in[4];
  float* out = (float*)d_out;

  char* ws = (char*)d_ws;
  ushort_t* x_bf     = (ushort_t*)(ws + 0);            // 32 MB; later pK/pV, then attn O
  float*    pK       = (float*)   (ws + 0);            // 16 MB (after gemm_qkv)
  float*    pV       = (float*)   (ws + 16777216);     // 16 MB
  ushort_t* wqkv_bf  = (ushort_t*)(ws + 33554432);     //  6 MB
  ushort_t* e_bf     = (ushort_t*)(ws + 39845888);     // 32 MB
  ushort_t* wproj_bf = (ushort_t*)(ws + 73400320);     //  2 MB
  ushort_t* q_bf     = (ushort_t*)(ws + 75497472);     // 32 MB
  ushort_t* kT       = (ushort_t*)(ws + 109051904);    // 32 MB
  ushort_t* vT       = (ushort_t*)(ws + 142606336);    // 32 MB
  ushort_t* klm      = (ushort_t*)(ws + 176160768);    //  2 MB
  ushort_t* vlmT     = (ushort_t*)(ws + 178257920);    //  2 MB
  // total: 180,355,072 bytes

  // 1) fused f32 -> bf16 converts (one dispatch)
  cvt_all<<<36864, 256, 0, stream>>>(x, x_bf, Wqkv, wqkv_bf, E, e_bf, Wproj, wproj_bf);

  // 2) fused QKV GEMM + repack -> q(n,d), kT(d,n), vT(d,n) bf16  [8-phase 256^2]
  gemm_qkv<<<768, 512, 0, stream>>>(x_bf, wqkv_bf, q_bf, kT, vT);

  // 3) landmark partials (both K and V), split-K over n: 4x4x64 = 1024 blocks
  lm_gemm<<<dim3(4, 4, 64), 256, 0, stream>>>(e_bf, kT, vT, pK, pV);

  // 4) reduce splits -> klm[z][k][d], vlmT[z][d][k]
  lm_reduce<<<dim3(4, 64), 256, 0, stream>>>(pK, pV, klm, vlmT);

  // 5) fused scores+softmax+PV -> attn_out (B,H,N,d) contiguous
  attn_fused<<<dim3(64, 1, 64), 256, 0, stream>>>(q_bf, klm, vlmT, x_bf);

  // 6) out = attn_out @ Wproj^T + bproj  [16384 x 1024] f32  [8-phase 256^2]
  gemm_nt_256<<<256, 512, 0, stream>>>(x_bf, wproj_bf, out, bproj);
}

// Round 5
// 437.430 us; speedup vs baseline: 1.1879x; 1.0301x over previous
//
#include <hip/hip_runtime.h>

// ---------------------------------------------------------------------------
// LinformerAttention on MI355X (gfx950) — round 12.
// B=4, N=4096, C=1024, H=16, K_LM=256, d=64.
// Baseline: round-10/11 kernel, verified 450.6 us; gemm_qkv 111.5 us
// (MfmaUtil 39%, FETCH 74 MB, conflicts 7.9e5 — stable).
// Round-4 post-mortem: lm_gemm bank swizzle = null -> lm_gemm is HBM-bound,
// not LDS-bound. Its traffic audit: E re-read x4 (z-sharing), kT/vT re-read
// x4 (kt-splitting) = ~384 MB + 67 MB partials; with (kt,s,z) grid the
// reusing blocks land on different XCDs -> L2 misses.
// Round-12 single experiment: XCD-chunked lm_gemm block remap (T1):
//   lin&7 = xcd owns h in {xcd, xcd+8}; within XCD order kt-fastest
//   (kT/vT slice L2-reuse), then zi (E slice L2-reuse), then s.
//   Pure bijective remap: same work, same occupancy, no sync changes.
// Everything else byte-identical to the 450.6 us run.
// ---------------------------------------------------------------------------

typedef unsigned short ushort_t;
typedef float f32x4 __attribute__((ext_vector_type(4)));
typedef __bf16 bf16x8 __attribute__((ext_vector_type(8)));
typedef unsigned short ushort8 __attribute__((ext_vector_type(8)));
typedef unsigned short ushort4_t __attribute__((ext_vector_type(4)));

__device__ inline ushort_t f2bf(float f) {
  unsigned int u = __float_as_uint(f);
  u += 0x7fff + ((u >> 16) & 1);   // RNE
  return (ushort_t)(u >> 16);
}

// async global -> LDS, 16 B per lane. LDS dest is wave-uniform base + lane*16.
__device__ inline void gload_lds16(const ushort_t* g, ushort_t* l) {
  __builtin_amdgcn_global_load_lds(
      (const __attribute__((address_space(1))) void*)g,
      (__attribute__((address_space(3))) void*)l, 16, 0, 0);
}

// --------------- fused f32 -> bf16 convert of all four inputs --------------
__global__ __launch_bounds__(256) void cvt_all(
    const float* __restrict__ x,  ushort_t* __restrict__ xo,
    const float* __restrict__ w1, ushort_t* __restrict__ w1o,
    const float* __restrict__ e,  ushort_t* __restrict__ eo,
    const float* __restrict__ w2, ushort_t* __restrict__ w2o) {
  // float4 chunk counts: x 4194304 | Wqkv 786432 | E 4194304 | Wproj 262144
  int i = blockIdx.x * blockDim.x + threadIdx.x;
  const float* in; ushort_t* out; int idx;
  if (i < 4194304)               { in = x;  out = xo;  idx = i; }
  else if (i < 4980736)          { in = w1; out = w1o; idx = i - 4194304; }
  else if (i < 9175040)          { in = e;  out = eo;  idx = i - 4980736; }
  else                           { in = w2; out = w2o; idx = i - 9175040; }
  float4 v = ((const float4*)in)[idx];
  ushort4_t o;
  o.x = f2bf(v.x); o.y = f2bf(v.y); o.z = f2bf(v.z); o.w = f2bf(v.w);
  ((ushort4_t*)out)[idx] = o;
}

// ===========================================================================
// 256x256 8-phase pipelined GEMM core (C = A @ B^T), K = 1024, bf16 in.
// 512 threads = 8 waves as wm(2) x wn(4). Per-wave output: two 64-row strips
// x two 32-col strips; quadrant (mh,nh) touches only LDS half-tiles
// A-h(mh) / B-h(nh).  (Round-8 schedule — verified 114.6/111.5 us.)
// LDS: A slot0 [0,32K) A slot1 [32K,64K) B slot0 [64K,96K) B slot1 [96K,128K).
// Swizzle: 16B slot s within a 128B row holds global k-chunk s ^ (row&7);
// global source pre-permuted, ds_read applies the same XOR.
// vmcnt ledger (stage order per tile [A0,B0,A1,B1], quadrants (0,0)(1,0)
// (1,1)(0,1)): waits 4/4/-/4, tail 2/0/-/-.
// ===========================================================================

#define BARX __builtin_amdgcn_s_barrier()
#define WVM(n) do { asm volatile("s_waitcnt vmcnt(" #n ")" ::: "memory"); \
                    __builtin_amdgcn_sched_barrier(0); } while (0)
#define WLG  do { asm volatile("s_waitcnt lgkmcnt(0)" ::: "memory"); \
                  __builtin_amdgcn_sched_barrier(0); } while (0)

#define STG_A(h, slot, tt) do { \
    gload_lds16(sA[h][0] + (tt) * 64, (ushort_t*)(smem + (slot) * 32768 + (h) * 16384 + (w * 2 + 0) * 1024)); \
    gload_lds16(sA[h][1] + (tt) * 64, (ushort_t*)(smem + (slot) * 32768 + (h) * 16384 + (w * 2 + 1) * 1024)); \
  } while (0)
#define STG_B(h, slot, tt) do { \
    gload_lds16(sB[h][0] + (tt) * 64, (ushort_t*)(smem + 65536 + (slot) * 32768 + (h) * 16384 + (w * 2 + 0) * 1024)); \
    gload_lds16(sB[h][1] + (tt) * 64, (ushort_t*)(smem + 65536 + (slot) * 32768 + (h) * 16384 + (w * 2 + 1) * 1024)); \
  } while (0)

#define RD_A(mh) do { \
    const char* ba_ = smem + sl * 32768 + ((mh) * 128 + wm * 64 + l15) * 128; \
    _Pragma("unroll") for (int i_ = 0; i_ < 4; i_++) { \
      aF[i_][0] = *(const bf16x8*)(ba_ + i_ * 2048 + cs0); \
      aF[i_][1] = *(const bf16x8*)(ba_ + i_ * 2048 + cs1); } \
  } while (0)
#define RD_B(nh) do { \
    const char* bb_ = smem + 65536 + sl * 32768 + ((nh) * 128 + wn * 32 + l15) * 128; \
    _Pragma("unroll") for (int j_ = 0; j_ < 2; j_++) { \
      bF[j_][0] = *(const bf16x8*)(bb_ + j_ * 2048 + cs0); \
      bF[j_][1] = *(const bf16x8*)(bb_ + j_ * 2048 + cs1); } \
  } while (0)

#define MQ(mh, nh) do { \
    _Pragma("unroll") for (int i_ = 0; i_ < 4; i_++) \
    _Pragma("unroll") for (int j_ = 0; j_ < 2; j_++) { \
      acc[(mh) * 4 + i_][(nh) * 2 + j_] = __builtin_amdgcn_mfma_f32_16x16x32_bf16( \
          aF[i_][0], bF[j_][0], acc[(mh) * 4 + i_][(nh) * 2 + j_], 0, 0, 0); \
      acc[(mh) * 4 + i_][(nh) * 2 + j_] = __builtin_amdgcn_mfma_f32_16x16x32_bf16( \
          aF[i_][1], bF[j_][1], acc[(mh) * 4 + i_][(nh) * 2 + j_], 0, 0, 0); } \
  } while (0)

__device__ __attribute__((always_inline)) inline void pipe256(
    const ushort_t* __restrict__ Ag, const ushort_t* __restrict__ Bg,
    long long m0, long long n0, char* smem, f32x4 acc[8][4]) {
  const int tid = threadIdx.x, lane = tid & 63, w = tid >> 6;
  const int l15 = lane & 15, quad = lane >> 4;
  const int wm = w >> 2, wn = w & 3;
  const int sw = l15 & 7;
  const int K = 1024;
  // swizzled ds_read byte offsets within a 128 B row, for k-step 0 / 1
  const int cs0 = ((0 * 4 + quad) ^ sw) << 4;
  const int cs1 = ((1 * 4 + quad) ^ sw) << 4;
  // staging source: lane L of chunk c=(w*2+q) covers LDS row c*8+(L>>3),
  // slot L&7 -> global k-chunk (L&7)^((L>>3)&7)  (row&7 == (L>>3)&7).
  const int lr8 = lane >> 3;
  const int sdat = ((lane & 7) ^ lr8) * 8;
  const ushort_t* sA[2][2];
  const ushort_t* sB[2][2];
#pragma unroll
  for (int h = 0; h < 2; h++)
#pragma unroll
    for (int q = 0; q < 2; q++) {
      sA[h][q] = Ag + (m0 + h * 128 + (w * 2 + q) * 8 + lr8) * K + sdat;
      sB[h][q] = Bg + (n0 + h * 128 + (w * 2 + q) * 8 + lr8) * K + sdat;
    }

  const f32x4 zz = {0.f, 0.f, 0.f, 0.f};
#pragma unroll
  for (int i = 0; i < 8; i++)
#pragma unroll
    for (int j = 0; j < 4; j++) acc[i][j] = zz;

  bf16x8 aF[4][2];   // current A half (re-read per quadrant as needed)
  bf16x8 bF[2][2];   // current B half

  // prologue: stage tile 0 (order A0,B0,A1,B1); need A0,B0 before ph0
  STG_A(0, 0, 0); STG_B(0, 0, 0); STG_A(1, 0, 0); STG_B(1, 0, 0);
  WVM(4);
  BARX;

#pragma unroll 2
  for (int t = 0; t < 16; ++t) {
    const int sl = t & 1, sn = sl ^ 1;
    const bool pf = (t < 15);
    // ---- phase 0: quadrant (0,0)
    RD_A(0); RD_B(0);
    if (pf) STG_A(0, sn, t + 1);
    BARX; WLG;
    __builtin_amdgcn_s_setprio(1); MQ(0, 0); __builtin_amdgcn_s_setprio(0);
    if (pf) { WVM(4); } else { WVM(2); }
    BARX;
    // ---- phase 1: quadrant (1,0)
    RD_A(1);
    if (pf) STG_B(0, sn, t + 1);
    BARX; WLG;
    __builtin_amdgcn_s_setprio(1); MQ(1, 0); __builtin_amdgcn_s_setprio(0);
    if (pf) { WVM(4); } else { WVM(0); }
    BARX;
    // ---- phase 2: quadrant (1,1)
    RD_B(1);
    if (pf) STG_A(1, sn, t + 1);
    BARX; WLG;
    __builtin_amdgcn_s_setprio(1); MQ(1, 1); __builtin_amdgcn_s_setprio(0);
    BARX;
    // ---- phase 3: quadrant (0,1)
    RD_A(0);
    if (pf) STG_B(1, sn, t + 1);
    BARX; WLG;
    __builtin_amdgcn_s_setprio(1); MQ(0, 1); __builtin_amdgcn_s_setprio(0);
    if (pf) WVM(4);
    BARX;
  }
}

// --------- fused QKV GEMM + repack:  qkv = x @ Wqkv^T, scatter to q/kT/vT --
// A = x_bf [16384][1024], W = wqkv_bf [3072][1024]. 256x256 tile, 8-phase.
// Grid: 768 blocks; xcd = lin&7 owns m-tiles [xcd*8, xcd*8+8) x all 12 n.
__global__ __launch_bounds__(512) void gemm_qkv(
    const ushort_t* __restrict__ A, const ushort_t* __restrict__ W,
    ushort_t* __restrict__ q, ushort_t* __restrict__ kT, ushort_t* __restrict__ vT) {
  __shared__ __align__(16) char smem[131072];
  const int lin = blockIdx.x;
  const int xcd = lin & 7, rr_ = lin >> 3;          // rr_ 0..95
  const int mt = xcd * 8 + (rr_ & 7);               // 0..63 (m-fastest in chunk)
  const int nt = rr_ >> 3;                          // 0..11
  const long long m0 = (long long)mt * 256;
  const long long n0 = (long long)nt * 256;

  f32x4 acc[8][4];
  pipe256(A, W, m0, n0, smem, acc);

  const int tid = threadIdx.x, lane = tid & 63, w = tid >> 6;
  const int l15 = lane & 15, quad = lane >> 4;
  const int wm = w >> 2, wn = w & 3;
  const int b     = (int)(m0 >> 12);
  const int nrow0 = (int)(m0 & 4095);
  const int s     = (int)(n0 >> 10);          // 0:q 1:k 2:v
  const int ncol0 = (int)(n0 & 1023);
  const int h0    = ncol0 >> 6;

  if (s == 0) {
#pragma unroll
    for (int mh = 0; mh < 2; mh++)
#pragma unroll
      for (int i = 0; i < 4; i++)
#pragma unroll
        for (int nh = 0; nh < 2; nh++)
#pragma unroll
          for (int j = 0; j < 2; j++) {
            int cx = ncol0 + nh * 128 + wn * 32 + j * 16;
            int h  = cx >> 6;
            int dd = (cx & 63) + l15;
            long long z = (long long)b * 16 + h;
            int nb = nrow0 + mh * 128 + wm * 64 + i * 16 + quad * 4;
#pragma unroll
            for (int r = 0; r < 4; r++)
              q[z * 262144 + (long long)(nb + r) * 64 + dd] = f2bf(acc[mh * 4 + i][nh * 2 + j][r]);
          }
  } else {
    // transpose through LDS in two 128-row passes: T[col 256][row 128 +pad]
    ushort_t (*T)[136] = (ushort_t(*)[136])smem;   // 256*136*2 = 69,632 B
    ushort_t* KV = (s == 1) ? kT : vT;
#pragma unroll
    for (int p = 0; p < 2; p++) {
      __syncthreads();
#pragma unroll
      for (int i = 0; i < 4; i++)
#pragma unroll
        for (int nh = 0; nh < 2; nh++)
#pragma unroll
          for (int j = 0; j < 2; j++) {
            int c = nh * 128 + wn * 32 + j * 16 + l15;
            int t = wm * 64 + i * 16 + quad * 4;
            ushort4_t o = {f2bf(acc[p * 4 + i][nh * 2 + j][0]), f2bf(acc[p * 4 + i][nh * 2 + j][1]),
                           f2bf(acc[p * 4 + i][nh * 2 + j][2]), f2bf(acc[p * 4 + i][nh * 2 + j][3])};
            *(ushort4_t*)(&T[c][t]) = o;
          }
      __syncthreads();
#pragma unroll
      for (int it = 0; it < 8; it++) {
        int ch = it * 512 + tid;
        int cl = ch >> 4, tc = (ch & 15) * 8;
        ushort8 v = *(const ushort8*)(&T[cl][tc]);
        int h = h0 + (cl >> 6), dd = cl & 63;
        long long z = (long long)b * 16 + h;
        *(ushort8*)(KV + z * 262144 + (long long)dd * 4096 + (nrow0 + p * 128 + tc)) = v;
      }
    }
  }
}

// ---- fused landmark partials: pK/pV[(z*4+s)*16384 + k*64 + d] -------------
//   = sum_{n in split s} E[h][k][n] * {kT,vT}[z][d][n]
// Round-12: XCD-chunked block remap (T1). lin&7 = xcd; xcd owns h in
// {xcd, xcd+8}. Within an h: kt fastest (kT/vT slice reused by 4 consecutive
// blocks on the same XCD), then zi (E[h][.][s-chunk] reused across the 4 z's
// sharing h), then s. Kernel body unchanged (both-sides XOR swizzle kept).
__global__ __launch_bounds__(256) void lm_gemm(
    const ushort_t* __restrict__ E, const ushort_t* __restrict__ kT,
    const ushort_t* __restrict__ vT, float* __restrict__ pK, float* __restrict__ pV) {
  __shared__ __align__(16) ushort_t smem[12288];  // E:0,2048  K:4096,6144  V:8192,10240
  const int tid = threadIdx.x, lane = tid & 63, w = tid >> 6;
  const int l15 = lane & 15, quad = lane >> 4;
  // ---- XCD-chunked decode (bijective on 0..1023) ----
  const int lin = blockIdx.x;
  const int xcd = lin & 7, idx = lin >> 3;   // idx 0..127
  const int h   = xcd + 8 * (idx >> 6);      // h 0..15: xcd owns {xcd, xcd+8}
  const int rem = idx & 63;
  const int kt  = rem & 3;                   // fastest: kT/vT slice L2-reuse
  const int zi  = (rem >> 2) & 3;            // next: E slice L2-reuse
  const int s   = rem >> 4;                  // 0..3
  const int z   = zi * 16 + h;               // z & 15 == h
  const int lr = lane >> 2;
  // pre-swizzled source column: chunk (lane&3) ^ ((lr>>1)&3), in 8-ushort units
  const int lc = ((lane & 3) ^ ((lr >> 1) & 3)) * 8;
  const int swz = (l15 >> 1) & 3;  // read-side swizzle (row & 15 == l15)

  const ushort_t* gE = E  + ((long long)h * 256 + kt * 64 + 16 * w + lr) * 4096 + s * 1024 + lc;
  const ushort_t* gK = kT + ((long long)z * 64 + 16 * w + lr) * 4096 + s * 1024 + lc;
  const ushort_t* gV = vT + ((long long)z * 64 + 16 * w + lr) * 4096 + s * 1024 + lc;
  ushort_t* lE = smem + 512 * w;
  ushort_t* lK = smem + 4096 + 512 * w;
  ushort_t* lV = smem + 8192 + 512 * w;

  const f32x4 zz = {0.f, 0.f, 0.f, 0.f};
  f32x4 aK[4], aV[4];
#pragma unroll
  for (int j = 0; j < 4; j++) { aK[j] = zz; aV[j] = zz; }

  for (int n = 0; n < 1024; n += 64) {
    __syncthreads();
#pragma unroll
    for (int p = 0; p < 2; p++) {
      gload_lds16(gE + n + 32 * p, lE + p * 2048);
      gload_lds16(gK + n + 32 * p, lK + p * 2048);
      gload_lds16(gV + n + 32 * p, lV + p * 2048);
    }
    __syncthreads();
#pragma unroll
    for (int p = 0; p < 2; p++) {
      bf16x8 ef = *(const bf16x8*)(smem + p * 2048 + (w * 16 + l15) * 32 + ((quad ^ swz) * 8));
#pragma unroll
      for (int j = 0; j < 4; j++) {
        bf16x8 kf = *(const bf16x8*)(smem + 4096 + p * 2048 + (j * 16 + l15) * 32 + ((quad ^ swz) * 8));
        aK[j] = __builtin_amdgcn_mfma_f32_16x16x32_bf16(ef, kf, aK[j], 0, 0, 0);
        bf16x8 vf = *(const bf16x8*)(smem + 8192 + p * 2048 + (j * 16 + l15) * 32 + ((quad ^ swz) * 8));
        aV[j] = __builtin_amdgcn_mfma_f32_16x16x32_bf16(ef, vf, aV[j], 0, 0, 0);
      }
    }
  }

  float* oK = pK + ((long long)(z * 4 + s) * 256 + kt * 64) * 64;
  float* oV = pV + ((long long)(z * 4 + s) * 256 + kt * 64) * 64;
#pragma unroll
  for (int j = 0; j < 4; j++)
#pragma unroll
    for (int r = 0; r < 4; r++) {
      int row = w * 16 + quad * 4 + r, col = j * 16 + l15;
      oK[row * 64 + col] = aK[j][r];
      oV[row * 64 + col] = aV[j][r];
    }
}

// ---- reduce 4 splits -> klm[z][k][d] bf16 and vlmT[z][d][k] bf16 ----------
__global__ __launch_bounds__(256) void lm_reduce(
    const float* __restrict__ pK, const float* __restrict__ pV,
    ushort_t* __restrict__ klm, ushort_t* __restrict__ vlmT) {
  __shared__ float Tv[64][68];
  const int tid = threadIdx.x;
  const int kt = blockIdx.x;   // 0..3
  const int z  = blockIdx.y;   // 0..63
  const long long base = (long long)z * 4 * 16384 + kt * 64 * 64;
  const int row = tid >> 2, c0 = (tid & 3) * 16;

  float sk[16];
#pragma unroll
  for (int g = 0; g < 4; g++) {
    f32x4 a = {0.f, 0.f, 0.f, 0.f};
#pragma unroll
    for (int s = 0; s < 4; s++)
      a += *(const f32x4*)(pK + base + (long long)s * 16384 + row * 64 + c0 + g * 4);
    sk[g * 4 + 0] = a[0]; sk[g * 4 + 1] = a[1]; sk[g * 4 + 2] = a[2]; sk[g * 4 + 3] = a[3];
  }
  {
    ushort_t* dst = klm + ((long long)z * 256 + kt * 64 + row) * 64 + c0;
    ushort8 o0, o1;
#pragma unroll
    for (int i = 0; i < 8; i++) { o0[i] = f2bf(sk[i]); o1[i] = f2bf(sk[8 + i]); }
    *(ushort8*)(dst) = o0;
    *(ushort8*)(dst + 8) = o1;
  }

#pragma unroll
  for (int g = 0; g < 4; g++) {
    f32x4 a = {0.f, 0.f, 0.f, 0.f};
#pragma unroll
    for (int s = 0; s < 4; s++)
      a += *(const f32x4*)(pV + base + (long long)s * 16384 + row * 64 + c0 + g * 4);
    *(f32x4*)(&Tv[row][c0 + g * 4]) = a;
  }
  __syncthreads();
  {
    ushort8 o0, o1;
#pragma unroll
    for (int i = 0; i < 8; i++) {
      o0[i] = f2bf(Tv[c0 + i][row]);
      o1[i] = f2bf(Tv[c0 + 8 + i][row]);
    }
    ushort_t* dst = vlmT + ((long long)z * 64 + row) * 256 + kt * 64 + c0;
    *(ushort8*)(dst) = o0;
    *(ushort8*)(dst + 8) = o1;
  }
}

// -------- fused flash-style: O = softmax(q@k_lm^T/8) @ v_lm  ---------------
__global__ __launch_bounds__(256) void attn_fused(
    const ushort_t* __restrict__ Q, const ushort_t* __restrict__ Klm,
    const ushort_t* __restrict__ VlmT, ushort_t* __restrict__ O) {
  __shared__ __align__(16) ushort_t smem[16896];          // 33,792 B
  ushort_t (*As)[40]  = (ushort_t(*)[40])smem;            // [64][40]
  ushort_t (*Bs)[40]  = (ushort_t(*)[40])(smem + 2560);   // [256][40]
  ushort_t (*P)[264]  = (ushort_t(*)[264])smem;           // [64][264] (aliases)
  const int tid = threadIdx.x, lane = tid & 63, w = tid >> 6;
  const int l15 = lane & 15, quad = lane >> 4;
  const int z = blockIdx.z;
  const long long m0 = (long long)blockIdx.x * 64;
  const ushort_t* Qb = Q + (long long)z * 262144;
  const ushort_t* Kb = Klm + (long long)z * 16384;
  const ushort_t* Vb = VlmT + (long long)z * 16384;

  const f32x4 zz = {0.f, 0.f, 0.f, 0.f};
  f32x4 acc[16];
#pragma unroll
  for (int j = 0; j < 16; j++) acc[j] = zz;

  const int sr = tid >> 2, sc = (tid & 3) * 8;

  // ---- phase 1: scores S[64][256] in registers ----
  for (int kt = 0; kt < 2; kt++) {
    const int k0 = kt * 32;
    ushort8 av = *(const ushort8*)(Qb + (m0 + sr) * 64 + k0 + sc);
    ushort8 bv[4];
#pragma unroll
    for (int r = 0; r < 4; r++) {
      int c = r * 256 + tid;
      bv[r] = *(const ushort8*)(Kb + (c >> 2) * 64 + k0 + (c & 3) * 8);
    }
    __syncthreads();
    *(ushort8*)(&As[sr][sc]) = av;
#pragma unroll
    for (int r = 0; r < 4; r++) {
      int c = r * 256 + tid;
      *(ushort8*)(&Bs[c >> 2][(c & 3) * 8]) = bv[r];
    }
    __syncthreads();
    bf16x8 af = *(const bf16x8*)(&As[w * 16 + l15][quad * 8]);
#pragma unroll
    for (int j = 0; j < 16; j++) {
      bf16x8 bfj = *(const bf16x8*)(&Bs[j * 16 + l15][quad * 8]);
      acc[j] = __builtin_amdgcn_mfma_f32_16x16x32_bf16(af, bfj, acc[j], 0, 0, 0);
    }
  }

  // ---- phase 2: softmax over 256 landmarks, P -> LDS (D-layout -> A-layout)
  __syncthreads();
#pragma unroll
  for (int r = 0; r < 4; r++) {
    float x[16];
    float vmax = -1e30f;
#pragma unroll
    for (int j = 0; j < 16; j++) { x[j] = acc[j][r] * 0.125f; vmax = fmaxf(vmax, x[j]); }
#pragma unroll
    for (int m = 1; m < 16; m <<= 1) vmax = fmaxf(vmax, __shfl_xor(vmax, m, 64));
    float s = 0.f;
#pragma unroll
    for (int j = 0; j < 16; j++) { x[j] = __expf(x[j] - vmax); s += x[j]; }
#pragma unroll
    for (int m = 1; m < 16; m <<= 1) s += __shfl_xor(s, m, 64);
    float inv = 1.0f / s;
    int row = w * 16 + quad * 4 + r;
#pragma unroll
    for (int j = 0; j < 16; j++)
      P[row][j * 16 + l15] = f2bf(x[j] * inv);
  }
  __syncthreads();

  // ---- phase 3: O[64][64] = P @ VlmT^T ----
  f32x4 o_acc[4];
#pragma unroll
  for (int j = 0; j < 4; j++) o_acc[j] = zz;
#pragma unroll
  for (int kc = 0; kc < 8; kc++) {
    bf16x8 pf = *(const bf16x8*)(&P[w * 16 + l15][kc * 32 + quad * 8]);
#pragma unroll
    for (int j = 0; j < 4; j++) {
      bf16x8 vf = *(const bf16x8*)(Vb + (j * 16 + l15) * 256 + kc * 32 + quad * 8);
      o_acc[j] = __builtin_amdgcn_mfma_f32_16x16x32_bf16(pf, vf, o_acc[j], 0, 0, 0);
    }
  }

#pragma unroll
  for (int j = 0; j < 4; j++)
#pragma unroll
    for (int r = 0; r < 4; r++) {
      int row = w * 16 + quad * 4 + r;
      int col = j * 16 + l15;
      O[(long long)z * 262144 + (m0 + row) * 64 + col] = f2bf(o_acc[j][r]);
    }
}

// ------------------- 256x256 tile NT GEMM, f32 out (+bias) -----------------
// A [16384][1024] bf16, B [1024][1024] bf16, C [16384][1024] f32.
// Grid: 256 blocks; xcd = lin&7 owns m-tiles [xcd*8, xcd*8+8) x all 4 n.
__global__ __launch_bounds__(512) void gemm_nt_256(
    const ushort_t* __restrict__ A, const ushort_t* __restrict__ B,
    float* __restrict__ C, const float* __restrict__ bias) {
  __shared__ __align__(16) char smem[131072];
  const int lin = blockIdx.x;
  const int xcd = lin & 7, rr_ = lin >> 3;          // rr_ 0..31
  const int mt = xcd * 8 + (rr_ & 7);               // 0..63
  const int nt = rr_ >> 3;                          // 0..3
  const long long m0 = (long long)mt * 256;
  const long long n0 = (long long)nt * 256;

  f32x4 acc[8][4];
  pipe256(A, B, m0, n0, smem, acc);

  const int tid = threadIdx.x, lane = tid & 63, w = tid >> 6;
  const int l15 = lane & 15, quad = lane >> 4;
  const int wm = w >> 2, wn = w & 3;

#pragma unroll
  for (int mh = 0; mh < 2; mh++)
#pragma unroll
    for (int i = 0; i < 4; i++)
#pragma unroll
      for (int nh = 0; nh < 2; nh++)
#pragma unroll
        for (int j = 0; j < 2; j++) {
          long long row = m0 + mh * 128 + wm * 64 + i * 16 + quad * 4;
          long long col = n0 + nh * 128 + wn * 32 + j * 16 + l15;
          float bv = bias[col];
#pragma unroll
          for (int r = 0; r < 4; r++)
            C[(row + r) * 1024 + col] = acc[mh * 4 + i][nh * 2 + j][r] + bv;
        }
}

// ---------------------------------------------------------------------------
extern "C" void kernel_launch(void* const* d_in, const int* in_sizes, int n_in,
                              void* d_out, int out_size, void* d_ws, size_t ws_size,
                              hipStream_t stream) {
  const float* x     = (const float*)d_in[0];
  const float* Wqkv  = (const float*)d_in[1];
  const float* E     = (const float*)d_in[2];
  const float* Wproj = (const float*)d_in[3];
  const float* bproj = (const float*)d_in[4];
  float* out = (float*)d_out;

  char* ws = (char*)d_ws;
  ushort_t* x_bf     = (ushort_t*)(ws + 0);            // 32 MB; later pK/pV, then attn O
  float*    pK       = (float*)   (ws + 0);            // 16 MB (after gemm_qkv)
  float*    pV       = (float*)   (ws + 16777216);     // 16 MB
  ushort_t* wqkv_bf  = (ushort_t*)(ws + 33554432);     //  6 MB
  ushort_t* e_bf     = (ushort_t*)(ws + 39845888);     // 32 MB
  ushort_t* wproj_bf = (ushort_t*)(ws + 73400320);     //  2 MB
  ushort_t* q_bf     = (ushort_t*)(ws + 75497472);     // 32 MB
  ushort_t* kT       = (ushort_t*)(ws + 109051904);    // 32 MB
  ushort_t* vT       = (ushort_t*)(ws + 142606336);    // 32 MB
  ushort_t* klm      = (ushort_t*)(ws + 176160768);    //  2 MB
  ushort_t* vlmT     = (ushort_t*)(ws + 178257920);    //  2 MB
  // total: 180,355,072 bytes

  // 1) fused f32 -> bf16 converts (one dispatch)
  cvt_all<<<36864, 256, 0, stream>>>(x, x_bf, Wqkv, wqkv_bf, E, e_bf, Wproj, wproj_bf);

  // 2) fused QKV GEMM + repack -> q(n,d), kT(d,n), vT(d,n) bf16  [8-phase 256^2]
  gemm_qkv<<<768, 512, 0, stream>>>(x_bf, wqkv_bf, q_bf, kT, vT);

  // 3) landmark partials, split-K over n; XCD-chunked remap (1024 blocks)
  lm_gemm<<<1024, 256, 0, stream>>>(e_bf, kT, vT, pK, pV);

  // 4) reduce splits -> klm[z][k][d], vlmT[z][d][k]
  lm_reduce<<<dim3(4, 64), 256, 0, stream>>>(pK, pV, klm, vlmT);

  // 5) fused scores+softmax+PV -> attn_out (B,H,N,d) contiguous
  attn_fused<<<dim3(64, 1, 64), 256, 0, stream>>>(q_bf, klm, vlmT, x_bf);

  // 6) out = attn_out @ Wproj^T + bproj  [16384 x 1024] f32  [8-phase 256^2]
  gemm_nt_256<<<256, 512, 0, stream>>>(x_bf, wproj_bf, out, bproj);
}

// Round 6
// 425.497 us; speedup vs baseline: 1.2212x; 1.0280x over previous
//
#include <hip/hip_runtime.h>

// ---------------------------------------------------------------------------
// LinformerAttention on MI355X (gfx950) — round 13.
// B=4, N=4096, C=1024, H=16, K_LM=256, d=64.
// Baseline: round-12, verified 437.4 us (qkv 112 us, MfmaUtil 39%).
// LDS-read audit: 32 b128/wave/K-tile = 256 KB/CU/tile = 3011 cyc vs 2064 cyc
// MFMA -> lock-step serialization = 5100 cyc/tile. Matches 112 us @ 39%.
// Round-13 single experiment: drop the ph3 A0 re-read (8 reads/wave/tile)
// by holding A-half-0 fragments in registers (aF0[4][2], +16 VGPR).
// Phase order, stage order, vmcnt ledger, barriers: BYTE-IDENTICAL to the
// verified r8 schedule. (r9's failure changed 3 things; this changes 1.)
// lm_gemm keeps the round-12 XCD-chunked remap (-13 us, confirmed).
// ---------------------------------------------------------------------------

typedef unsigned short ushort_t;
typedef float f32x4 __attribute__((ext_vector_type(4)));
typedef __bf16 bf16x8 __attribute__((ext_vector_type(8)));
typedef unsigned short ushort8 __attribute__((ext_vector_type(8)));
typedef unsigned short ushort4_t __attribute__((ext_vector_type(4)));

__device__ inline ushort_t f2bf(float f) {
  unsigned int u = __float_as_uint(f);
  u += 0x7fff + ((u >> 16) & 1);   // RNE
  return (ushort_t)(u >> 16);
}

// async global -> LDS, 16 B per lane. LDS dest is wave-uniform base + lane*16.
__device__ inline void gload_lds16(const ushort_t* g, ushort_t* l) {
  __builtin_amdgcn_global_load_lds(
      (const __attribute__((address_space(1))) void*)g,
      (__attribute__((address_space(3))) void*)l, 16, 0, 0);
}

// --------------- fused f32 -> bf16 convert of all four inputs --------------
__global__ __launch_bounds__(256) void cvt_all(
    const float* __restrict__ x,  ushort_t* __restrict__ xo,
    const float* __restrict__ w1, ushort_t* __restrict__ w1o,
    const float* __restrict__ e,  ushort_t* __restrict__ eo,
    const float* __restrict__ w2, ushort_t* __restrict__ w2o) {
  // float4 chunk counts: x 4194304 | Wqkv 786432 | E 4194304 | Wproj 262144
  int i = blockIdx.x * blockDim.x + threadIdx.x;
  const float* in; ushort_t* out; int idx;
  if (i < 4194304)               { in = x;  out = xo;  idx = i; }
  else if (i < 4980736)          { in = w1; out = w1o; idx = i - 4194304; }
  else if (i < 9175040)          { in = e;  out = eo;  idx = i - 4980736; }
  else                           { in = w2; out = w2o; idx = i - 9175040; }
  float4 v = ((const float4*)in)[idx];
  ushort4_t o;
  o.x = f2bf(v.x); o.y = f2bf(v.y); o.z = f2bf(v.z); o.w = f2bf(v.w);
  ((ushort4_t*)out)[idx] = o;
}

// ===========================================================================
// 256x256 8-phase pipelined GEMM core (C = A @ B^T), K = 1024, bf16 in.
// 512 threads = 8 waves as wm(2) x wn(4). Quadrant (mh,nh) touches only LDS
// half-tiles A-h(mh)/B-h(nh).  r8 schedule + A0 held in regs (r13):
//   ph0 (0,0): RD A0->aF0, B0->bF | ph1 (1,0): RD A1->aF1 (bF held)
//   ph2 (1,1): RD B1->bF (aF1 held) | ph3 (0,1): NO READ (aF0, bF held)
// LDS: A slot0 [0,32K) A slot1 [32K,64K) B slot0 [64K,96K) B slot1 [96K,128K).
// Swizzle: 16B slot s within a 128B row holds global k-chunk s ^ (row&7);
// global source pre-permuted, ds_read applies the same XOR.
// vmcnt ledger (stage order per tile [A0,B0,A1,B1]): waits 4/4/-/4, tail 2/0/-/-.
// ===========================================================================

#define BARX __builtin_amdgcn_s_barrier()
#define WVM(n) do { asm volatile("s_waitcnt vmcnt(" #n ")" ::: "memory"); \
                    __builtin_amdgcn_sched_barrier(0); } while (0)
#define WLG  do { asm volatile("s_waitcnt lgkmcnt(0)" ::: "memory"); \
                  __builtin_amdgcn_sched_barrier(0); } while (0)

#define STG_A(h, slot, tt) do { \
    gload_lds16(sA[h][0] + (tt) * 64, (ushort_t*)(smem + (slot) * 32768 + (h) * 16384 + (w * 2 + 0) * 1024)); \
    gload_lds16(sA[h][1] + (tt) * 64, (ushort_t*)(smem + (slot) * 32768 + (h) * 16384 + (w * 2 + 1) * 1024)); \
  } while (0)
#define STG_B(h, slot, tt) do { \
    gload_lds16(sB[h][0] + (tt) * 64, (ushort_t*)(smem + 65536 + (slot) * 32768 + (h) * 16384 + (w * 2 + 0) * 1024)); \
    gload_lds16(sB[h][1] + (tt) * 64, (ushort_t*)(smem + 65536 + (slot) * 32768 + (h) * 16384 + (w * 2 + 1) * 1024)); \
  } while (0)

#define RD_A(mh, AF) do { \
    const char* ba_ = smem + sl * 32768 + ((mh) * 128 + wm * 64 + l15) * 128; \
    _Pragma("unroll") for (int i_ = 0; i_ < 4; i_++) { \
      AF[i_][0] = *(const bf16x8*)(ba_ + i_ * 2048 + cs0); \
      AF[i_][1] = *(const bf16x8*)(ba_ + i_ * 2048 + cs1); } \
  } while (0)
#define RD_B(nh) do { \
    const char* bb_ = smem + 65536 + sl * 32768 + ((nh) * 128 + wn * 32 + l15) * 128; \
    _Pragma("unroll") for (int j_ = 0; j_ < 2; j_++) { \
      bF[j_][0] = *(const bf16x8*)(bb_ + j_ * 2048 + cs0); \
      bF[j_][1] = *(const bf16x8*)(bb_ + j_ * 2048 + cs1); } \
  } while (0)

#define MQ(mh, nh, AF) do { \
    _Pragma("unroll") for (int i_ = 0; i_ < 4; i_++) \
    _Pragma("unroll") for (int j_ = 0; j_ < 2; j_++) { \
      acc[(mh) * 4 + i_][(nh) * 2 + j_] = __builtin_amdgcn_mfma_f32_16x16x32_bf16( \
          AF[i_][0], bF[j_][0], acc[(mh) * 4 + i_][(nh) * 2 + j_], 0, 0, 0); \
      acc[(mh) * 4 + i_][(nh) * 2 + j_] = __builtin_amdgcn_mfma_f32_16x16x32_bf16( \
          AF[i_][1], bF[j_][1], acc[(mh) * 4 + i_][(nh) * 2 + j_], 0, 0, 0); } \
  } while (0)

__device__ __attribute__((always_inline)) inline void pipe256(
    const ushort_t* __restrict__ Ag, const ushort_t* __restrict__ Bg,
    long long m0, long long n0, char* smem, f32x4 acc[8][4]) {
  const int tid = threadIdx.x, lane = tid & 63, w = tid >> 6;
  const int l15 = lane & 15, quad = lane >> 4;
  const int wm = w >> 2, wn = w & 3;
  const int sw = l15 & 7;
  const int K = 1024;
  // swizzled ds_read byte offsets within a 128 B row, for k-step 0 / 1
  const int cs0 = ((0 * 4 + quad) ^ sw) << 4;
  const int cs1 = ((1 * 4 + quad) ^ sw) << 4;
  // staging source: lane L of chunk c=(w*2+q) covers LDS row c*8+(L>>3),
  // slot L&7 -> global k-chunk (L&7)^((L>>3)&7)  (row&7 == (L>>3)&7).
  const int lr8 = lane >> 3;
  const int sdat = ((lane & 7) ^ lr8) * 8;
  const ushort_t* sA[2][2];
  const ushort_t* sB[2][2];
#pragma unroll
  for (int h = 0; h < 2; h++)
#pragma unroll
    for (int q = 0; q < 2; q++) {
      sA[h][q] = Ag + (m0 + h * 128 + (w * 2 + q) * 8 + lr8) * K + sdat;
      sB[h][q] = Bg + (n0 + h * 128 + (w * 2 + q) * 8 + lr8) * K + sdat;
    }

  const f32x4 zz = {0.f, 0.f, 0.f, 0.f};
#pragma unroll
  for (int i = 0; i < 8; i++)
#pragma unroll
    for (int j = 0; j < 4; j++) acc[i][j] = zz;

  bf16x8 aF0[4][2];  // A half 0 — read in ph0, HELD through ph3
  bf16x8 aF1[4][2];  // A half 1 — read in ph1, used ph1/ph2
  bf16x8 bF[2][2];   // current B half (held across adjacent phases as in r8)

  // prologue: stage tile 0 (order A0,B0,A1,B1); need A0,B0 before ph0
  STG_A(0, 0, 0); STG_B(0, 0, 0); STG_A(1, 0, 0); STG_B(1, 0, 0);
  WVM(4);
  BARX;

#pragma unroll 2
  for (int t = 0; t < 16; ++t) {
    const int sl = t & 1, sn = sl ^ 1;
    const bool pf = (t < 15);
    // ---- phase 0: quadrant (0,0)
    RD_A(0, aF0); RD_B(0);
    if (pf) STG_A(0, sn, t + 1);
    BARX; WLG;
    __builtin_amdgcn_s_setprio(1); MQ(0, 0, aF0); __builtin_amdgcn_s_setprio(0);
    if (pf) { WVM(4); } else { WVM(2); }
    BARX;
    // ---- phase 1: quadrant (1,0)
    RD_A(1, aF1);
    if (pf) STG_B(0, sn, t + 1);
    BARX; WLG;
    __builtin_amdgcn_s_setprio(1); MQ(1, 0, aF1); __builtin_amdgcn_s_setprio(0);
    if (pf) { WVM(4); } else { WVM(0); }
    BARX;
    // ---- phase 2: quadrant (1,1)
    RD_B(1);
    if (pf) STG_A(1, sn, t + 1);
    BARX; WLG;
    __builtin_amdgcn_s_setprio(1); MQ(1, 1, aF1); __builtin_amdgcn_s_setprio(0);
    BARX;
    // ---- phase 3: quadrant (0,1) — aF0 + bF both held, NO LDS read
    if (pf) STG_B(1, sn, t + 1);
    BARX; WLG;
    __builtin_amdgcn_s_setprio(1); MQ(0, 1, aF0); __builtin_amdgcn_s_setprio(0);
    if (pf) WVM(4);
    BARX;
  }
}

// --------- fused QKV GEMM + repack:  qkv = x @ Wqkv^T, scatter to q/kT/vT --
// A = x_bf [16384][1024], W = wqkv_bf [3072][1024]. 256x256 tile, 8-phase.
// Grid: 768 blocks; xcd = lin&7 owns m-tiles [xcd*8, xcd*8+8) x all 12 n.
__global__ __launch_bounds__(512) void gemm_qkv(
    const ushort_t* __restrict__ A, const ushort_t* __restrict__ W,
    ushort_t* __restrict__ q, ushort_t* __restrict__ kT, ushort_t* __restrict__ vT) {
  __shared__ __align__(16) char smem[131072];
  const int lin = blockIdx.x;
  const int xcd = lin & 7, rr_ = lin >> 3;          // rr_ 0..95
  const int mt = xcd * 8 + (rr_ & 7);               // 0..63 (m-fastest in chunk)
  const int nt = rr_ >> 3;                          // 0..11
  const long long m0 = (long long)mt * 256;
  const long long n0 = (long long)nt * 256;

  f32x4 acc[8][4];
  pipe256(A, W, m0, n0, smem, acc);

  const int tid = threadIdx.x, lane = tid & 63, w = tid >> 6;
  const int l15 = lane & 15, quad = lane >> 4;
  const int wm = w >> 2, wn = w & 3;
  const int b     = (int)(m0 >> 12);
  const int nrow0 = (int)(m0 & 4095);
  const int s     = (int)(n0 >> 10);          // 0:q 1:k 2:v
  const int ncol0 = (int)(n0 & 1023);
  const int h0    = ncol0 >> 6;

  if (s == 0) {
#pragma unroll
    for (int mh = 0; mh < 2; mh++)
#pragma unroll
      for (int i = 0; i < 4; i++)
#pragma unroll
        for (int nh = 0; nh < 2; nh++)
#pragma unroll
          for (int j = 0; j < 2; j++) {
            int cx = ncol0 + nh * 128 + wn * 32 + j * 16;
            int h  = cx >> 6;
            int dd = (cx & 63) + l15;
            long long z = (long long)b * 16 + h;
            int nb = nrow0 + mh * 128 + wm * 64 + i * 16 + quad * 4;
#pragma unroll
            for (int r = 0; r < 4; r++)
              q[z * 262144 + (long long)(nb + r) * 64 + dd] = f2bf(acc[mh * 4 + i][nh * 2 + j][r]);
          }
  } else {
    // transpose through LDS in two 128-row passes: T[col 256][row 128 +pad]
    ushort_t (*T)[136] = (ushort_t(*)[136])smem;   // 256*136*2 = 69,632 B
    ushort_t* KV = (s == 1) ? kT : vT;
#pragma unroll
    for (int p = 0; p < 2; p++) {
      __syncthreads();
#pragma unroll
      for (int i = 0; i < 4; i++)
#pragma unroll
        for (int nh = 0; nh < 2; nh++)
#pragma unroll
          for (int j = 0; j < 2; j++) {
            int c = nh * 128 + wn * 32 + j * 16 + l15;
            int t = wm * 64 + i * 16 + quad * 4;
            ushort4_t o = {f2bf(acc[p * 4 + i][nh * 2 + j][0]), f2bf(acc[p * 4 + i][nh * 2 + j][1]),
                           f2bf(acc[p * 4 + i][nh * 2 + j][2]), f2bf(acc[p * 4 + i][nh * 2 + j][3])};
            *(ushort4_t*)(&T[c][t]) = o;
          }
      __syncthreads();
#pragma unroll
      for (int it = 0; it < 8; it++) {
        int ch = it * 512 + tid;
        int cl = ch >> 4, tc = (ch & 15) * 8;
        ushort8 v = *(const ushort8*)(&T[cl][tc]);
        int h = h0 + (cl >> 6), dd = cl & 63;
        long long z = (long long)b * 16 + h;
        *(ushort8*)(KV + z * 262144 + (long long)dd * 4096 + (nrow0 + p * 128 + tc)) = v;
      }
    }
  }
}

// ---- fused landmark partials: pK/pV[(z*4+s)*16384 + k*64 + d] -------------
//   = sum_{n in split s} E[h][k][n] * {kT,vT}[z][d][n]
// XCD-chunked block remap (T1, r12, -13 us confirmed). lin&7 = xcd; xcd owns
// h in {xcd, xcd+8}; within: kt fastest, then zi, then s.
__global__ __launch_bounds__(256) void lm_gemm(
    const ushort_t* __restrict__ E, const ushort_t* __restrict__ kT,
    const ushort_t* __restrict__ vT, float* __restrict__ pK, float* __restrict__ pV) {
  __shared__ __align__(16) ushort_t smem[12288];  // E:0,2048  K:4096,6144  V:8192,10240
  const int tid = threadIdx.x, lane = tid & 63, w = tid >> 6;
  const int l15 = lane & 15, quad = lane >> 4;
  // ---- XCD-chunked decode (bijective on 0..1023) ----
  const int lin = blockIdx.x;
  const int xcd = lin & 7, idx = lin >> 3;   // idx 0..127
  const int h   = xcd + 8 * (idx >> 6);      // h 0..15: xcd owns {xcd, xcd+8}
  const int rem = idx & 63;
  const int kt  = rem & 3;                   // fastest: kT/vT slice L2-reuse
  const int zi  = (rem >> 2) & 3;            // next: E slice L2-reuse
  const int s   = rem >> 4;                  // 0..3
  const int z   = zi * 16 + h;               // z & 15 == h
  const int lr = lane >> 2;
  // pre-swizzled source column: chunk (lane&3) ^ ((lr>>1)&3), in 8-ushort units
  const int lc = ((lane & 3) ^ ((lr >> 1) & 3)) * 8;
  const int swz = (l15 >> 1) & 3;  // read-side swizzle (row & 15 == l15)

  const ushort_t* gE = E  + ((long long)h * 256 + kt * 64 + 16 * w + lr) * 4096 + s * 1024 + lc;
  const ushort_t* gK = kT + ((long long)z * 64 + 16 * w + lr) * 4096 + s * 1024 + lc;
  const ushort_t* gV = vT + ((long long)z * 64 + 16 * w + lr) * 4096 + s * 1024 + lc;
  ushort_t* lE = smem + 512 * w;
  ushort_t* lK = smem + 4096 + 512 * w;
  ushort_t* lV = smem + 8192 + 512 * w;

  const f32x4 zz = {0.f, 0.f, 0.f, 0.f};
  f32x4 aK[4], aV[4];
#pragma unroll
  for (int j = 0; j < 4; j++) { aK[j] = zz; aV[j] = zz; }

  for (int n = 0; n < 1024; n += 64) {
    __syncthreads();
#pragma unroll
    for (int p = 0; p < 2; p++) {
      gload_lds16(gE + n + 32 * p, lE + p * 2048);
      gload_lds16(gK + n + 32 * p, lK + p * 2048);
      gload_lds16(gV + n + 32 * p, lV + p * 2048);
    }
    __syncthreads();
#pragma unroll
    for (int p = 0; p < 2; p++) {
      bf16x8 ef = *(const bf16x8*)(smem + p * 2048 + (w * 16 + l15) * 32 + ((quad ^ swz) * 8));
#pragma unroll
      for (int j = 0; j < 4; j++) {
        bf16x8 kf = *(const bf16x8*)(smem + 4096 + p * 2048 + (j * 16 + l15) * 32 + ((quad ^ swz) * 8));
        aK[j] = __builtin_amdgcn_mfma_f32_16x16x32_bf16(ef, kf, aK[j], 0, 0, 0);
        bf16x8 vf = *(const bf16x8*)(smem + 8192 + p * 2048 + (j * 16 + l15) * 32 + ((quad ^ swz) * 8));
        aV[j] = __builtin_amdgcn_mfma_f32_16x16x32_bf16(ef, vf, aV[j], 0, 0, 0);
      }
    }
  }

  float* oK = pK + ((long long)(z * 4 + s) * 256 + kt * 64) * 64;
  float* oV = pV + ((long long)(z * 4 + s) * 256 + kt * 64) * 64;
#pragma unroll
  for (int j = 0; j < 4; j++)
#pragma unroll
    for (int r = 0; r < 4; r++) {
      int row = w * 16 + quad * 4 + r, col = j * 16 + l15;
      oK[row * 64 + col] = aK[j][r];
      oV[row * 64 + col] = aV[j][r];
    }
}

// ---- reduce 4 splits -> klm[z][k][d] bf16 and vlmT[z][d][k] bf16 ----------
__global__ __launch_bounds__(256) void lm_reduce(
    const float* __restrict__ pK, const float* __restrict__ pV,
    ushort_t* __restrict__ klm, ushort_t* __restrict__ vlmT) {
  __shared__ float Tv[64][68];
  const int tid = threadIdx.x;
  const int kt = blockIdx.x;   // 0..3
  const int z  = blockIdx.y;   // 0..63
  const long long base = (long long)z * 4 * 16384 + kt * 64 * 64;
  const int row = tid >> 2, c0 = (tid & 3) * 16;

  float sk[16];
#pragma unroll
  for (int g = 0; g < 4; g++) {
    f32x4 a = {0.f, 0.f, 0.f, 0.f};
#pragma unroll
    for (int s = 0; s < 4; s++)
      a += *(const f32x4*)(pK + base + (long long)s * 16384 + row * 64 + c0 + g * 4);
    sk[g * 4 + 0] = a[0]; sk[g * 4 + 1] = a[1]; sk[g * 4 + 2] = a[2]; sk[g * 4 + 3] = a[3];
  }
  {
    ushort_t* dst = klm + ((long long)z * 256 + kt * 64 + row) * 64 + c0;
    ushort8 o0, o1;
#pragma unroll
    for (int i = 0; i < 8; i++) { o0[i] = f2bf(sk[i]); o1[i] = f2bf(sk[8 + i]); }
    *(ushort8*)(dst) = o0;
    *(ushort8*)(dst + 8) = o1;
  }

#pragma unroll
  for (int g = 0; g < 4; g++) {
    f32x4 a = {0.f, 0.f, 0.f, 0.f};
#pragma unroll
    for (int s = 0; s < 4; s++)
      a += *(const f32x4*)(pV + base + (long long)s * 16384 + row * 64 + c0 + g * 4);
    *(f32x4*)(&Tv[row][c0 + g * 4]) = a;
  }
  __syncthreads();
  {
    ushort8 o0, o1;
#pragma unroll
    for (int i = 0; i < 8; i++) {
      o0[i] = f2bf(Tv[c0 + i][row]);
      o1[i] = f2bf(Tv[c0 + 8 + i][row]);
    }
    ushort_t* dst = vlmT + ((long long)z * 64 + row) * 256 + kt * 64 + c0;
    *(ushort8*)(dst) = o0;
    *(ushort8*)(dst + 8) = o1;
  }
}

// -------- fused flash-style: O = softmax(q@k_lm^T/8) @ v_lm  ---------------
__global__ __launch_bounds__(256) void attn_fused(
    const ushort_t* __restrict__ Q, const ushort_t* __restrict__ Klm,
    const ushort_t* __restrict__ VlmT, ushort_t* __restrict__ O) {
  __shared__ __align__(16) ushort_t smem[16896];          // 33,792 B
  ushort_t (*As)[40]  = (ushort_t(*)[40])smem;            // [64][40]
  ushort_t (*Bs)[40]  = (ushort_t(*)[40])(smem + 2560);   // [256][40]
  ushort_t (*P)[264]  = (ushort_t(*)[264])smem;           // [64][264] (aliases)
  const int tid = threadIdx.x, lane = tid & 63, w = tid >> 6;
  const int l15 = lane & 15, quad = lane >> 4;
  const int z = blockIdx.z;
  const long long m0 = (long long)blockIdx.x * 64;
  const ushort_t* Qb = Q + (long long)z * 262144;
  const ushort_t* Kb = Klm + (long long)z * 16384;
  const ushort_t* Vb = VlmT + (long long)z * 16384;

  const f32x4 zz = {0.f, 0.f, 0.f, 0.f};
  f32x4 acc[16];
#pragma unroll
  for (int j = 0; j < 16; j++) acc[j] = zz;

  const int sr = tid >> 2, sc = (tid & 3) * 8;

  // ---- phase 1: scores S[64][256] in registers ----
  for (int kt = 0; kt < 2; kt++) {
    const int k0 = kt * 32;
    ushort8 av = *(const ushort8*)(Qb + (m0 + sr) * 64 + k0 + sc);
    ushort8 bv[4];
#pragma unroll
    for (int r = 0; r < 4; r++) {
      int c = r * 256 + tid;
      bv[r] = *(const ushort8*)(Kb + (c >> 2) * 64 + k0 + (c & 3) * 8);
    }
    __syncthreads();
    *(ushort8*)(&As[sr][sc]) = av;
#pragma unroll
    for (int r = 0; r < 4; r++) {
      int c = r * 256 + tid;
      *(ushort8*)(&Bs[c >> 2][(c & 3) * 8]) = bv[r];
    }
    __syncthreads();
    bf16x8 af = *(const bf16x8*)(&As[w * 16 + l15][quad * 8]);
#pragma unroll
    for (int j = 0; j < 16; j++) {
      bf16x8 bfj = *(const bf16x8*)(&Bs[j * 16 + l15][quad * 8]);
      acc[j] = __builtin_amdgcn_mfma_f32_16x16x32_bf16(af, bfj, acc[j], 0, 0, 0);
    }
  }

  // ---- phase 2: softmax over 256 landmarks, P -> LDS (D-layout -> A-layout)
  __syncthreads();
#pragma unroll
  for (int r = 0; r < 4; r++) {
    float x[16];
    float vmax = -1e30f;
#pragma unroll
    for (int j = 0; j < 16; j++) { x[j] = acc[j][r] * 0.125f; vmax = fmaxf(vmax, x[j]); }
#pragma unroll
    for (int m = 1; m < 16; m <<= 1) vmax = fmaxf(vmax, __shfl_xor(vmax, m, 64));
    float s = 0.f;
#pragma unroll
    for (int j = 0; j < 16; j++) { x[j] = __expf(x[j] - vmax); s += x[j]; }
#pragma unroll
    for (int m = 1; m < 16; m <<= 1) s += __shfl_xor(s, m, 64);
    float inv = 1.0f / s;
    int row = w * 16 + quad * 4 + r;
#pragma unroll
    for (int j = 0; j < 16; j++)
      P[row][j * 16 + l15] = f2bf(x[j] * inv);
  }
  __syncthreads();

  // ---- phase 3: O[64][64] = P @ VlmT^T ----
  f32x4 o_acc[4];
#pragma unroll
  for (int j = 0; j < 4; j++) o_acc[j] = zz;
#pragma unroll
  for (int kc = 0; kc < 8; kc++) {
    bf16x8 pf = *(const bf16x8*)(&P[w * 16 + l15][kc * 32 + quad * 8]);
#pragma unroll
    for (int j = 0; j < 4; j++) {
      bf16x8 vf = *(const bf16x8*)(Vb + (j * 16 + l15) * 256 + kc * 32 + quad * 8);
      o_acc[j] = __builtin_amdgcn_mfma_f32_16x16x32_bf16(pf, vf, o_acc[j], 0, 0, 0);
    }
  }

#pragma unroll
  for (int j = 0; j < 4; j++)
#pragma unroll
    for (int r = 0; r < 4; r++) {
      int row = w * 16 + quad * 4 + r;
      int col = j * 16 + l15;
      O[(long long)z * 262144 + (m0 + row) * 64 + col] = f2bf(o_acc[j][r]);
    }
}

// ------------------- 256x256 tile NT GEMM, f32 out (+bias) -----------------
// A [16384][1024] bf16, B [1024][1024] bf16, C [16384][1024] f32.
// Grid: 256 blocks; xcd = lin&7 owns m-tiles [xcd*8, xcd*8+8) x all 4 n.
__global__ __launch_bounds__(512) void gemm_nt_256(
    const ushort_t* __restrict__ A, const ushort_t* __restrict__ B,
    float* __restrict__ C, const float* __restrict__ bias) {
  __shared__ __align__(16) char smem[131072];
  const int lin = blockIdx.x;
  const int xcd = lin & 7, rr_ = lin >> 3;          // rr_ 0..31
  const int mt = xcd * 8 + (rr_ & 7);               // 0..63
  const int nt = rr_ >> 3;                          // 0..3
  const long long m0 = (long long)mt * 256;
  const long long n0 = (long long)nt * 256;

  f32x4 acc[8][4];
  pipe256(A, B, m0, n0, smem, acc);

  const int tid = threadIdx.x, lane = tid & 63, w = tid >> 6;
  const int l15 = lane & 15, quad = lane >> 4;
  const int wm = w >> 2, wn = w & 3;

#pragma unroll
  for (int mh = 0; mh < 2; mh++)
#pragma unroll
    for (int i = 0; i < 4; i++)
#pragma unroll
      for (int nh = 0; nh < 2; nh++)
#pragma unroll
        for (int j = 0; j < 2; j++) {
          long long row = m0 + mh * 128 + wm * 64 + i * 16 + quad * 4;
          long long col = n0 + nh * 128 + wn * 32 + j * 16 + l15;
          float bv = bias[col];
#pragma unroll
          for (int r = 0; r < 4; r++)
            C[(row + r) * 1024 + col] = acc[mh * 4 + i][nh * 2 + j][r] + bv;
        }
}

// ---------------------------------------------------------------------------
extern "C" void kernel_launch(void* const* d_in, const int* in_sizes, int n_in,
                              void* d_out, int out_size, void* d_ws, size_t ws_size,
                              hipStream_t stream) {
  const float* x     = (const float*)d_in[0];
  const float* Wqkv  = (const float*)d_in[1];
  const float* E     = (const float*)d_in[2];
  const float* Wproj = (const float*)d_in[3];
  const float* bproj = (const float*)d_in[4];
  float* out = (float*)d_out;

  char* ws = (char*)d_ws;
  ushort_t* x_bf     = (ushort_t*)(ws + 0);            // 32 MB; later pK/pV, then attn O
  float*    pK       = (float*)   (ws + 0);            // 16 MB (after gemm_qkv)
  float*    pV       = (float*)   (ws + 16777216);     // 16 MB
  ushort_t* wqkv_bf  = (ushort_t*)(ws + 33554432);     //  6 MB
  ushort_t* e_bf     = (ushort_t*)(ws + 39845888);     // 32 MB
  ushort_t* wproj_bf = (ushort_t*)(ws + 73400320);     //  2 MB
  ushort_t* q_bf     = (ushort_t*)(ws + 75497472);     // 32 MB
  ushort_t* kT       = (ushort_t*)(ws + 109051904);    // 32 MB
  ushort_t* vT       = (ushort_t*)(ws + 142606336);    // 32 MB
  ushort_t* klm      = (ushort_t*)(ws + 176160768);    //  2 MB
  ushort_t* vlmT     = (ushort_t*)(ws + 178257920);    //  2 MB
  // total: 180,355,072 bytes

  // 1) fused f32 -> bf16 converts (one dispatch)
  cvt_all<<<36864, 256, 0, stream>>>(x, x_bf, Wqkv, wqkv_bf, E, e_bf, Wproj, wproj_bf);

  // 2) fused QKV GEMM + repack -> q(n,d), kT(d,n), vT(d,n) bf16  [8-phase 256^2]
  gemm_qkv<<<768, 512, 0, stream>>>(x_bf, wqkv_bf, q_bf, kT, vT);

  // 3) landmark partials, split-K over n; XCD-chunked remap (1024 blocks)
  lm_gemm<<<1024, 256, 0, stream>>>(e_bf, kT, vT, pK, pV);

  // 4) reduce splits -> klm[z][k][d], vlmT[z][d][k]
  lm_reduce<<<dim3(4, 64), 256, 0, stream>>>(pK, pV, klm, vlmT);

  // 5) fused scores+softmax+PV -> attn_out (B,H,N,d) contiguous
  attn_fused<<<dim3(64, 1, 64), 256, 0, stream>>>(q_bf, klm, vlmT, x_bf);

  // 6) out = attn_out @ Wproj^T + bproj  [16384 x 1024] f32  [8-phase 256^2]
  gemm_nt_256<<<256, 512, 0, stream>>>(x_bf, wproj_bf, out, bproj);
}

// Round 7
// 420.916 us; speedup vs baseline: 1.2345x; 1.0109x over previous
//
#include <hip/hip_runtime.h>

// ---------------------------------------------------------------------------
// LinformerAttention on MI355X (gfx950) — round 14.
// B=4, N=4096, C=1024, H=16, K_LM=256, d=64.
// Baseline: round-13, verified 425.5 us (qkv 107 us @ MfmaUtil 41.2%, VGPR
// still 128; A0-hold confirmed +5 us; reads/wave/tile now at the 24 floor).
// Round-14 single experiment: lm_gemm counted-vmcnt double-buffer pipeline.
//   Old loop: {syncthreads; stage 6; syncthreads(=vmcnt(0) drain); compute}
//   -> exposes HBM latency every step (m97-class drain stall).
//   New loop: 32-col panels, 2 buffers x 12 KB (same 24 KB total -> still
//   4 blocks/CU), stage panel t+1 (3 gloads) -> vmcnt(3) (panel t landed,
//   t+1 stays in flight) -> barrier -> compute(t) -> barrier.
//   Swizzle, XCD remap, epilogue, split-K all unchanged.
// ---------------------------------------------------------------------------

typedef unsigned short ushort_t;
typedef float f32x4 __attribute__((ext_vector_type(4)));
typedef __bf16 bf16x8 __attribute__((ext_vector_type(8)));
typedef unsigned short ushort8 __attribute__((ext_vector_type(8)));
typedef unsigned short ushort4_t __attribute__((ext_vector_type(4)));

__device__ inline ushort_t f2bf(float f) {
  unsigned int u = __float_as_uint(f);
  u += 0x7fff + ((u >> 16) & 1);   // RNE
  return (ushort_t)(u >> 16);
}

// async global -> LDS, 16 B per lane. LDS dest is wave-uniform base + lane*16.
__device__ inline void gload_lds16(const ushort_t* g, ushort_t* l) {
  __builtin_amdgcn_global_load_lds(
      (const __attribute__((address_space(1))) void*)g,
      (__attribute__((address_space(3))) void*)l, 16, 0, 0);
}

// --------------- fused f32 -> bf16 convert of all four inputs --------------
__global__ __launch_bounds__(256) void cvt_all(
    const float* __restrict__ x,  ushort_t* __restrict__ xo,
    const float* __restrict__ w1, ushort_t* __restrict__ w1o,
    const float* __restrict__ e,  ushort_t* __restrict__ eo,
    const float* __restrict__ w2, ushort_t* __restrict__ w2o) {
  // float4 chunk counts: x 4194304 | Wqkv 786432 | E 4194304 | Wproj 262144
  int i = blockIdx.x * blockDim.x + threadIdx.x;
  const float* in; ushort_t* out; int idx;
  if (i < 4194304)               { in = x;  out = xo;  idx = i; }
  else if (i < 4980736)          { in = w1; out = w1o; idx = i - 4194304; }
  else if (i < 9175040)          { in = e;  out = eo;  idx = i - 4980736; }
  else                           { in = w2; out = w2o; idx = i - 9175040; }
  float4 v = ((const float4*)in)[idx];
  ushort4_t o;
  o.x = f2bf(v.x); o.y = f2bf(v.y); o.z = f2bf(v.z); o.w = f2bf(v.w);
  ((ushort4_t*)out)[idx] = o;
}

// ===========================================================================
// 256x256 8-phase pipelined GEMM core (C = A @ B^T), K = 1024, bf16 in.
// 512 threads = 8 waves as wm(2) x wn(4). Quadrant (mh,nh) touches only LDS
// half-tiles A-h(mh)/B-h(nh).  r8 schedule + A0 held in regs (r13):
//   ph0 (0,0): RD A0->aF0, B0->bF | ph1 (1,0): RD A1->aF1 (bF held)
//   ph2 (1,1): RD B1->bF (aF1 held) | ph3 (0,1): NO READ (aF0, bF held)
// LDS: A slot0 [0,32K) A slot1 [32K,64K) B slot0 [64K,96K) B slot1 [96K,128K).
// Swizzle: 16B slot s within a 128B row holds global k-chunk s ^ (row&7);
// global source pre-permuted, ds_read applies the same XOR.
// vmcnt ledger (stage order per tile [A0,B0,A1,B1]): waits 4/4/-/4, tail 2/0/-/-.
// ===========================================================================

#define BARX __builtin_amdgcn_s_barrier()
#define WVM(n) do { asm volatile("s_waitcnt vmcnt(" #n ")" ::: "memory"); \
                    __builtin_amdgcn_sched_barrier(0); } while (0)
#define WLG  do { asm volatile("s_waitcnt lgkmcnt(0)" ::: "memory"); \
                  __builtin_amdgcn_sched_barrier(0); } while (0)

#define STG_A(h, slot, tt) do { \
    gload_lds16(sA[h][0] + (tt) * 64, (ushort_t*)(smem + (slot) * 32768 + (h) * 16384 + (w * 2 + 0) * 1024)); \
    gload_lds16(sA[h][1] + (tt) * 64, (ushort_t*)(smem + (slot) * 32768 + (h) * 16384 + (w * 2 + 1) * 1024)); \
  } while (0)
#define STG_B(h, slot, tt) do { \
    gload_lds16(sB[h][0] + (tt) * 64, (ushort_t*)(smem + 65536 + (slot) * 32768 + (h) * 16384 + (w * 2 + 0) * 1024)); \
    gload_lds16(sB[h][1] + (tt) * 64, (ushort_t*)(smem + 65536 + (slot) * 32768 + (h) * 16384 + (w * 2 + 1) * 1024)); \
  } while (0)

#define RD_A(mh, AF) do { \
    const char* ba_ = smem + sl * 32768 + ((mh) * 128 + wm * 64 + l15) * 128; \
    _Pragma("unroll") for (int i_ = 0; i_ < 4; i_++) { \
      AF[i_][0] = *(const bf16x8*)(ba_ + i_ * 2048 + cs0); \
      AF[i_][1] = *(const bf16x8*)(ba_ + i_ * 2048 + cs1); } \
  } while (0)
#define RD_B(nh) do { \
    const char* bb_ = smem + 65536 + sl * 32768 + ((nh) * 128 + wn * 32 + l15) * 128; \
    _Pragma("unroll") for (int j_ = 0; j_ < 2; j_++) { \
      bF[j_][0] = *(const bf16x8*)(bb_ + j_ * 2048 + cs0); \
      bF[j_][1] = *(const bf16x8*)(bb_ + j_ * 2048 + cs1); } \
  } while (0)

#define MQ(mh, nh, AF) do { \
    _Pragma("unroll") for (int i_ = 0; i_ < 4; i_++) \
    _Pragma("unroll") for (int j_ = 0; j_ < 2; j_++) { \
      acc[(mh) * 4 + i_][(nh) * 2 + j_] = __builtin_amdgcn_mfma_f32_16x16x32_bf16( \
          AF[i_][0], bF[j_][0], acc[(mh) * 4 + i_][(nh) * 2 + j_], 0, 0, 0); \
      acc[(mh) * 4 + i_][(nh) * 2 + j_] = __builtin_amdgcn_mfma_f32_16x16x32_bf16( \
          AF[i_][1], bF[j_][1], acc[(mh) * 4 + i_][(nh) * 2 + j_], 0, 0, 0); } \
  } while (0)

__device__ __attribute__((always_inline)) inline void pipe256(
    const ushort_t* __restrict__ Ag, const ushort_t* __restrict__ Bg,
    long long m0, long long n0, char* smem, f32x4 acc[8][4]) {
  const int tid = threadIdx.x, lane = tid & 63, w = tid >> 6;
  const int l15 = lane & 15, quad = lane >> 4;
  const int wm = w >> 2, wn = w & 3;
  const int sw = l15 & 7;
  const int K = 1024;
  // swizzled ds_read byte offsets within a 128 B row, for k-step 0 / 1
  const int cs0 = ((0 * 4 + quad) ^ sw) << 4;
  const int cs1 = ((1 * 4 + quad) ^ sw) << 4;
  // staging source: lane L of chunk c=(w*2+q) covers LDS row c*8+(L>>3),
  // slot L&7 -> global k-chunk (L&7)^((L>>3)&7)  (row&7 == (L>>3)&7).
  const int lr8 = lane >> 3;
  const int sdat = ((lane & 7) ^ lr8) * 8;
  const ushort_t* sA[2][2];
  const ushort_t* sB[2][2];
#pragma unroll
  for (int h = 0; h < 2; h++)
#pragma unroll
    for (int q = 0; q < 2; q++) {
      sA[h][q] = Ag + (m0 + h * 128 + (w * 2 + q) * 8 + lr8) * K + sdat;
      sB[h][q] = Bg + (n0 + h * 128 + (w * 2 + q) * 8 + lr8) * K + sdat;
    }

  const f32x4 zz = {0.f, 0.f, 0.f, 0.f};
#pragma unroll
  for (int i = 0; i < 8; i++)
#pragma unroll
    for (int j = 0; j < 4; j++) acc[i][j] = zz;

  bf16x8 aF0[4][2];  // A half 0 — read in ph0, HELD through ph3
  bf16x8 aF1[4][2];  // A half 1 — read in ph1, used ph1/ph2
  bf16x8 bF[2][2];   // current B half (held across adjacent phases as in r8)

  // prologue: stage tile 0 (order A0,B0,A1,B1); need A0,B0 before ph0
  STG_A(0, 0, 0); STG_B(0, 0, 0); STG_A(1, 0, 0); STG_B(1, 0, 0);
  WVM(4);
  BARX;

#pragma unroll 2
  for (int t = 0; t < 16; ++t) {
    const int sl = t & 1, sn = sl ^ 1;
    const bool pf = (t < 15);
    // ---- phase 0: quadrant (0,0)
    RD_A(0, aF0); RD_B(0);
    if (pf) STG_A(0, sn, t + 1);
    BARX; WLG;
    __builtin_amdgcn_s_setprio(1); MQ(0, 0, aF0); __builtin_amdgcn_s_setprio(0);
    if (pf) { WVM(4); } else { WVM(2); }
    BARX;
    // ---- phase 1: quadrant (1,0)
    RD_A(1, aF1);
    if (pf) STG_B(0, sn, t + 1);
    BARX; WLG;
    __builtin_amdgcn_s_setprio(1); MQ(1, 0, aF1); __builtin_amdgcn_s_setprio(0);
    if (pf) { WVM(4); } else { WVM(0); }
    BARX;
    // ---- phase 2: quadrant (1,1)
    RD_B(1);
    if (pf) STG_A(1, sn, t + 1);
    BARX; WLG;
    __builtin_amdgcn_s_setprio(1); MQ(1, 1, aF1); __builtin_amdgcn_s_setprio(0);
    BARX;
    // ---- phase 3: quadrant (0,1) — aF0 + bF both held, NO LDS read
    if (pf) STG_B(1, sn, t + 1);
    BARX; WLG;
    __builtin_amdgcn_s_setprio(1); MQ(0, 1, aF0); __builtin_amdgcn_s_setprio(0);
    if (pf) WVM(4);
    BARX;
  }
}

// --------- fused QKV GEMM + repack:  qkv = x @ Wqkv^T, scatter to q/kT/vT --
// A = x_bf [16384][1024], W = wqkv_bf [3072][1024]. 256x256 tile, 8-phase.
// Grid: 768 blocks; xcd = lin&7 owns m-tiles [xcd*8, xcd*8+8) x all 12 n.
__global__ __launch_bounds__(512) void gemm_qkv(
    const ushort_t* __restrict__ A, const ushort_t* __restrict__ W,
    ushort_t* __restrict__ q, ushort_t* __restrict__ kT, ushort_t* __restrict__ vT) {
  __shared__ __align__(16) char smem[131072];
  const int lin = blockIdx.x;
  const int xcd = lin & 7, rr_ = lin >> 3;          // rr_ 0..95
  const int mt = xcd * 8 + (rr_ & 7);               // 0..63 (m-fastest in chunk)
  const int nt = rr_ >> 3;                          // 0..11
  const long long m0 = (long long)mt * 256;
  const long long n0 = (long long)nt * 256;

  f32x4 acc[8][4];
  pipe256(A, W, m0, n0, smem, acc);

  const int tid = threadIdx.x, lane = tid & 63, w = tid >> 6;
  const int l15 = lane & 15, quad = lane >> 4;
  const int wm = w >> 2, wn = w & 3;
  const int b     = (int)(m0 >> 12);
  const int nrow0 = (int)(m0 & 4095);
  const int s     = (int)(n0 >> 10);          // 0:q 1:k 2:v
  const int ncol0 = (int)(n0 & 1023);
  const int h0    = ncol0 >> 6;

  if (s == 0) {
#pragma unroll
    for (int mh = 0; mh < 2; mh++)
#pragma unroll
      for (int i = 0; i < 4; i++)
#pragma unroll
        for (int nh = 0; nh < 2; nh++)
#pragma unroll
          for (int j = 0; j < 2; j++) {
            int cx = ncol0 + nh * 128 + wn * 32 + j * 16;
            int h  = cx >> 6;
            int dd = (cx & 63) + l15;
            long long z = (long long)b * 16 + h;
            int nb = nrow0 + mh * 128 + wm * 64 + i * 16 + quad * 4;
#pragma unroll
            for (int r = 0; r < 4; r++)
              q[z * 262144 + (long long)(nb + r) * 64 + dd] = f2bf(acc[mh * 4 + i][nh * 2 + j][r]);
          }
  } else {
    // transpose through LDS in two 128-row passes: T[col 256][row 128 +pad]
    ushort_t (*T)[136] = (ushort_t(*)[136])smem;   // 256*136*2 = 69,632 B
    ushort_t* KV = (s == 1) ? kT : vT;
#pragma unroll
    for (int p = 0; p < 2; p++) {
      __syncthreads();
#pragma unroll
      for (int i = 0; i < 4; i++)
#pragma unroll
        for (int nh = 0; nh < 2; nh++)
#pragma unroll
          for (int j = 0; j < 2; j++) {
            int c = nh * 128 + wn * 32 + j * 16 + l15;
            int t = wm * 64 + i * 16 + quad * 4;
            ushort4_t o = {f2bf(acc[p * 4 + i][nh * 2 + j][0]), f2bf(acc[p * 4 + i][nh * 2 + j][1]),
                           f2bf(acc[p * 4 + i][nh * 2 + j][2]), f2bf(acc[p * 4 + i][nh * 2 + j][3])};
            *(ushort4_t*)(&T[c][t]) = o;
          }
      __syncthreads();
#pragma unroll
      for (int it = 0; it < 8; it++) {
        int ch = it * 512 + tid;
        int cl = ch >> 4, tc = (ch & 15) * 8;
        ushort8 v = *(const ushort8*)(&T[cl][tc]);
        int h = h0 + (cl >> 6), dd = cl & 63;
        long long z = (long long)b * 16 + h;
        *(ushort8*)(KV + z * 262144 + (long long)dd * 4096 + (nrow0 + p * 128 + tc)) = v;
      }
    }
  }
}

// ---- fused landmark partials: pK/pV[(z*4+s)*16384 + k*64 + d] -------------
//   = sum_{n in split s} E[h][k][n] * {kT,vT}[z][d][n]
// XCD-chunked remap (r12, confirmed) + NEW counted-vmcnt double-buffer (r14):
// 32-col panels, 2 buffers x 12 KB (24 KB total, 4 blocks/CU kept);
// stage panel t+1 (3 gloads) -> vmcnt(3) -> barrier -> compute(t) -> barrier.
#define LMSTG(b_, t_) do { \
    ushort_t* base_ = smem + (b_) * 6144; \
    gload_lds16(gE + (t_) * 32, base_ + 512 * w); \
    gload_lds16(gK + (t_) * 32, base_ + 2048 + 512 * w); \
    gload_lds16(gV + (t_) * 32, base_ + 4096 + 512 * w); \
  } while (0)

#define LMCMP(b_) do { \
    const ushort_t* base_ = smem + (b_) * 6144; \
    bf16x8 ef = *(const bf16x8*)(base_ + (w * 16 + l15) * 32 + ((quad ^ swz) * 8)); \
    _Pragma("unroll") for (int j_ = 0; j_ < 4; j_++) { \
      bf16x8 kf = *(const bf16x8*)(base_ + 2048 + (j_ * 16 + l15) * 32 + ((quad ^ swz) * 8)); \
      aK[j_] = __builtin_amdgcn_mfma_f32_16x16x32_bf16(ef, kf, aK[j_], 0, 0, 0); \
      bf16x8 vf = *(const bf16x8*)(base_ + 4096 + (j_ * 16 + l15) * 32 + ((quad ^ swz) * 8)); \
      aV[j_] = __builtin_amdgcn_mfma_f32_16x16x32_bf16(ef, vf, aV[j_], 0, 0, 0); \
    } } while (0)

__global__ __launch_bounds__(256) void lm_gemm(
    const ushort_t* __restrict__ E, const ushort_t* __restrict__ kT,
    const ushort_t* __restrict__ vT, float* __restrict__ pK, float* __restrict__ pV) {
  __shared__ __align__(16) ushort_t smem[12288];  // 2 buffers x [E 2048|K 2048|V 2048]
  const int tid = threadIdx.x, lane = tid & 63, w = tid >> 6;
  const int l15 = lane & 15, quad = lane >> 4;
  // ---- XCD-chunked decode (bijective on 0..1023) ----
  const int lin = blockIdx.x;
  const int xcd = lin & 7, idx = lin >> 3;   // idx 0..127
  const int h   = xcd + 8 * (idx >> 6);      // h 0..15: xcd owns {xcd, xcd+8}
  const int rem = idx & 63;
  const int kt  = rem & 3;                   // fastest: kT/vT slice L2-reuse
  const int zi  = (rem >> 2) & 3;            // next: E slice L2-reuse
  const int s   = rem >> 4;                  // 0..3
  const int z   = zi * 16 + h;               // z & 15 == h
  const int lr = lane >> 2;
  // pre-swizzled source column: chunk (lane&3) ^ ((lr>>1)&3), in 8-ushort units
  const int lc = ((lane & 3) ^ ((lr >> 1) & 3)) * 8;
  const int swz = (l15 >> 1) & 3;  // read-side swizzle (row & 15 == l15)

  const ushort_t* gE = E  + ((long long)h * 256 + kt * 64 + 16 * w + lr) * 4096 + s * 1024 + lc;
  const ushort_t* gK = kT + ((long long)z * 64 + 16 * w + lr) * 4096 + s * 1024 + lc;
  const ushort_t* gV = vT + ((long long)z * 64 + 16 * w + lr) * 4096 + s * 1024 + lc;

  const f32x4 zz = {0.f, 0.f, 0.f, 0.f};
  f32x4 aK[4], aV[4];
#pragma unroll
  for (int j = 0; j < 4; j++) { aK[j] = zz; aV[j] = zz; }

  // counted-vmcnt double-buffer pipeline over 32 panels of 32 n-cols
  LMSTG(0, 0);
#pragma unroll 2
  for (int t = 0; t < 31; ++t) {
    const int b = t & 1;
    LMSTG(b ^ 1, t + 1);   // issue next panel (3 loads) -> 6 outstanding
    WVM(3);                 // panel t's 3 landed; t+1 stays in flight
    BARX;
    LMCMP(b);
    BARX;                   // all reads of buffer b done before overwrite
  }
  WVM(0);
  BARX;
  LMCMP(1);                 // panel 31 (buffer 31&1 = 1)

  float* oK = pK + ((long long)(z * 4 + s) * 256 + kt * 64) * 64;
  float* oV = pV + ((long long)(z * 4 + s) * 256 + kt * 64) * 64;
#pragma unroll
  for (int j = 0; j < 4; j++)
#pragma unroll
    for (int r = 0; r < 4; r++) {
      int row = w * 16 + quad * 4 + r, col = j * 16 + l15;
      oK[row * 64 + col] = aK[j][r];
      oV[row * 64 + col] = aV[j][r];
    }
}

// ---- reduce 4 splits -> klm[z][k][d] bf16 and vlmT[z][d][k] bf16 ----------
__global__ __launch_bounds__(256) void lm_reduce(
    const float* __restrict__ pK, const float* __restrict__ pV,
    ushort_t* __restrict__ klm, ushort_t* __restrict__ vlmT) {
  __shared__ float Tv[64][68];
  const int tid = threadIdx.x;
  const int kt = blockIdx.x;   // 0..3
  const int z  = blockIdx.y;   // 0..63
  const long long base = (long long)z * 4 * 16384 + kt * 64 * 64;
  const int row = tid >> 2, c0 = (tid & 3) * 16;

  float sk[16];
#pragma unroll
  for (int g = 0; g < 4; g++) {
    f32x4 a = {0.f, 0.f, 0.f, 0.f};
#pragma unroll
    for (int s = 0; s < 4; s++)
      a += *(const f32x4*)(pK + base + (long long)s * 16384 + row * 64 + c0 + g * 4);
    sk[g * 4 + 0] = a[0]; sk[g * 4 + 1] = a[1]; sk[g * 4 + 2] = a[2]; sk[g * 4 + 3] = a[3];
  }
  {
    ushort_t* dst = klm + ((long long)z * 256 + kt * 64 + row) * 64 + c0;
    ushort8 o0, o1;
#pragma unroll
    for (int i = 0; i < 8; i++) { o0[i] = f2bf(sk[i]); o1[i] = f2bf(sk[8 + i]); }
    *(ushort8*)(dst) = o0;
    *(ushort8*)(dst + 8) = o1;
  }

#pragma unroll
  for (int g = 0; g < 4; g++) {
    f32x4 a = {0.f, 0.f, 0.f, 0.f};
#pragma unroll
    for (int s = 0; s < 4; s++)
      a += *(const f32x4*)(pV + base + (long long)s * 16384 + row * 64 + c0 + g * 4);
    *(f32x4*)(&Tv[row][c0 + g * 4]) = a;
  }
  __syncthreads();
  {
    ushort8 o0, o1;
#pragma unroll
    for (int i = 0; i < 8; i++) {
      o0[i] = f2bf(Tv[c0 + i][row]);
      o1[i] = f2bf(Tv[c0 + 8 + i][row]);
    }
    ushort_t* dst = vlmT + ((long long)z * 64 + row) * 256 + kt * 64 + c0;
    *(ushort8*)(dst) = o0;
    *(ushort8*)(dst + 8) = o1;
  }
}

// -------- fused flash-style: O = softmax(q@k_lm^T/8) @ v_lm  ---------------
__global__ __launch_bounds__(256) void attn_fused(
    const ushort_t* __restrict__ Q, const ushort_t* __restrict__ Klm,
    const ushort_t* __restrict__ VlmT, ushort_t* __restrict__ O) {
  __shared__ __align__(16) ushort_t smem[16896];          // 33,792 B
  ushort_t (*As)[40]  = (ushort_t(*)[40])smem;            // [64][40]
  ushort_t (*Bs)[40]  = (ushort_t(*)[40])(smem + 2560);   // [256][40]
  ushort_t (*P)[264]  = (ushort_t(*)[264])smem;           // [64][264] (aliases)
  const int tid = threadIdx.x, lane = tid & 63, w = tid >> 6;
  const int l15 = lane & 15, quad = lane >> 4;
  const int z = blockIdx.z;
  const long long m0 = (long long)blockIdx.x * 64;
  const ushort_t* Qb = Q + (long long)z * 262144;
  const ushort_t* Kb = Klm + (long long)z * 16384;
  const ushort_t* Vb = VlmT + (long long)z * 16384;

  const f32x4 zz = {0.f, 0.f, 0.f, 0.f};
  f32x4 acc[16];
#pragma unroll
  for (int j = 0; j < 16; j++) acc[j] = zz;

  const int sr = tid >> 2, sc = (tid & 3) * 8;

  // ---- phase 1: scores S[64][256] in registers ----
  for (int kt = 0; kt < 2; kt++) {
    const int k0 = kt * 32;
    ushort8 av = *(const ushort8*)(Qb + (m0 + sr) * 64 + k0 + sc);
    ushort8 bv[4];
#pragma unroll
    for (int r = 0; r < 4; r++) {
      int c = r * 256 + tid;
      bv[r] = *(const ushort8*)(Kb + (c >> 2) * 64 + k0 + (c & 3) * 8);
    }
    __syncthreads();
    *(ushort8*)(&As[sr][sc]) = av;
#pragma unroll
    for (int r = 0; r < 4; r++) {
      int c = r * 256 + tid;
      *(ushort8*)(&Bs[c >> 2][(c & 3) * 8]) = bv[r];
    }
    __syncthreads();
    bf16x8 af = *(const bf16x8*)(&As[w * 16 + l15][quad * 8]);
#pragma unroll
    for (int j = 0; j < 16; j++) {
      bf16x8 bfj = *(const bf16x8*)(&Bs[j * 16 + l15][quad * 8]);
      acc[j] = __builtin_amdgcn_mfma_f32_16x16x32_bf16(af, bfj, acc[j], 0, 0, 0);
    }
  }

  // ---- phase 2: softmax over 256 landmarks, P -> LDS (D-layout -> A-layout)
  __syncthreads();
#pragma unroll
  for (int r = 0; r < 4; r++) {
    float x[16];
    float vmax = -1e30f;
#pragma unroll
    for (int j = 0; j < 16; j++) { x[j] = acc[j][r] * 0.125f; vmax = fmaxf(vmax, x[j]); }
#pragma unroll
    for (int m = 1; m < 16; m <<= 1) vmax = fmaxf(vmax, __shfl_xor(vmax, m, 64));
    float s = 0.f;
#pragma unroll
    for (int j = 0; j < 16; j++) { x[j] = __expf(x[j] - vmax); s += x[j]; }
#pragma unroll
    for (int m = 1; m < 16; m <<= 1) s += __shfl_xor(s, m, 64);
    float inv = 1.0f / s;
    int row = w * 16 + quad * 4 + r;
#pragma unroll
    for (int j = 0; j < 16; j++)
      P[row][j * 16 + l15] = f2bf(x[j] * inv);
  }
  __syncthreads();

  // ---- phase 3: O[64][64] = P @ VlmT^T ----
  f32x4 o_acc[4];
#pragma unroll
  for (int j = 0; j < 4; j++) o_acc[j] = zz;
#pragma unroll
  for (int kc = 0; kc < 8; kc++) {
    bf16x8 pf = *(const bf16x8*)(&P[w * 16 + l15][kc * 32 + quad * 8]);
#pragma unroll
    for (int j = 0; j < 4; j++) {
      bf16x8 vf = *(const bf16x8*)(Vb + (j * 16 + l15) * 256 + kc * 32 + quad * 8);
      o_acc[j] = __builtin_amdgcn_mfma_f32_16x16x32_bf16(pf, vf, o_acc[j], 0, 0, 0);
    }
  }

#pragma unroll
  for (int j = 0; j < 4; j++)
#pragma unroll
    for (int r = 0; r < 4; r++) {
      int row = w * 16 + quad * 4 + r;
      int col = j * 16 + l15;
      O[(long long)z * 262144 + (m0 + row) * 64 + col] = f2bf(o_acc[j][r]);
    }
}

// ------------------- 256x256 tile NT GEMM, f32 out (+bias) -----------------
// A [16384][1024] bf16, B [1024][1024] bf16, C [16384][1024] f32.
// Grid: 256 blocks; xcd = lin&7 owns m-tiles [xcd*8, xcd*8+8) x all 4 n.
__global__ __launch_bounds__(512) void gemm_nt_256(
    const ushort_t* __restrict__ A, const ushort_t* __restrict__ B,
    float* __restrict__ C, const float* __restrict__ bias) {
  __shared__ __align__(16) char smem[131072];
  const int lin = blockIdx.x;
  const int xcd = lin & 7, rr_ = lin >> 3;          // rr_ 0..31
  const int mt = xcd * 8 + (rr_ & 7);               // 0..63
  const int nt = rr_ >> 3;                          // 0..3
  const long long m0 = (long long)mt * 256;
  const long long n0 = (long long)nt * 256;

  f32x4 acc[8][4];
  pipe256(A, B, m0, n0, smem, acc);

  const int tid = threadIdx.x, lane = tid & 63, w = tid >> 6;
  const int l15 = lane & 15, quad = lane >> 4;
  const int wm = w >> 2, wn = w & 3;

#pragma unroll
  for (int mh = 0; mh < 2; mh++)
#pragma unroll
    for (int i = 0; i < 4; i++)
#pragma unroll
      for (int nh = 0; nh < 2; nh++)
#pragma unroll
        for (int j = 0; j < 2; j++) {
          long long row = m0 + mh * 128 + wm * 64 + i * 16 + quad * 4;
          long long col = n0 + nh * 128 + wn * 32 + j * 16 + l15;
          float bv = bias[col];
#pragma unroll
          for (int r = 0; r < 4; r++)
            C[(row + r) * 1024 + col] = acc[mh * 4 + i][nh * 2 + j][r] + bv;
        }
}

// ---------------------------------------------------------------------------
extern "C" void kernel_launch(void* const* d_in, const int* in_sizes, int n_in,
                              void* d_out, int out_size, void* d_ws, size_t ws_size,
                              hipStream_t stream) {
  const float* x     = (const float*)d_in[0];
  const float* Wqkv  = (const float*)d_in[1];
  const float* E     = (const float*)d_in[2];
  const float* Wproj = (const float*)d_in[3];
  const float* bproj = (const float*)d_in[4];
  float* out = (float*)d_out;

  char* ws = (char*)d_ws;
  ushort_t* x_bf     = (ushort_t*)(ws + 0);            // 32 MB; later pK/pV, then attn O
  float*    pK       = (float*)   (ws + 0);            // 16 MB (after gemm_qkv)
  float*    pV       = (float*)   (ws + 16777216);     // 16 MB
  ushort_t* wqkv_bf  = (ushort_t*)(ws + 33554432);     //  6 MB
  ushort_t* e_bf     = (ushort_t*)(ws + 39845888);     // 32 MB
  ushort_t* wproj_bf = (ushort_t*)(ws + 73400320);     //  2 MB
  ushort_t* q_bf     = (ushort_t*)(ws + 75497472);     // 32 MB
  ushort_t* kT       = (ushort_t*)(ws + 109051904);    // 32 MB
  ushort_t* vT       = (ushort_t*)(ws + 142606336);    // 32 MB
  ushort_t* klm      = (ushort_t*)(ws + 176160768);    //  2 MB
  ushort_t* vlmT     = (ushort_t*)(ws + 178257920);    //  2 MB
  // total: 180,355,072 bytes

  // 1) fused f32 -> bf16 converts (one dispatch)
  cvt_all<<<36864, 256, 0, stream>>>(x, x_bf, Wqkv, wqkv_bf, E, e_bf, Wproj, wproj_bf);

  // 2) fused QKV GEMM + repack -> q(n,d), kT(d,n), vT(d,n) bf16  [8-phase 256^2]
  gemm_qkv<<<768, 512, 0, stream>>>(x_bf, wqkv_bf, q_bf, kT, vT);

  // 3) landmark partials, split-K over n; XCD remap + counted-vmcnt pipeline
  lm_gemm<<<1024, 256, 0, stream>>>(e_bf, kT, vT, pK, pV);

  // 4) reduce splits -> klm[z][k][d], vlmT[z][d][k]
  lm_reduce<<<dim3(4, 64), 256, 0, stream>>>(pK, pV, klm, vlmT);

  // 5) fused scores+softmax+PV -> attn_out (B,H,N,d) contiguous
  attn_fused<<<dim3(64, 1, 64), 256, 0, stream>>>(q_bf, klm, vlmT, x_bf);

  // 6) out = attn_out @ Wproj^T + bproj  [16384 x 1024] f32  [8-phase 256^2]
  gemm_nt_256<<<256, 512, 0, stream>>>(x_bf, wproj_bf, out, bproj);
}